// Round 16
// baseline (1548.184 us; speedup 1.0000x reference)
//
#include <hip/hip_runtime.h>
#include <hip/hip_fp16.h>
#include <stdint.h>

#define H 128
#define FN 133
#define FE 14
#define NG 1024
#define APAD 133

typedef float v2f __attribute__((ext_vector_type(2)));
typedef _Float16 f16x8 __attribute__((ext_vector_type(8)));
typedef float f32x4 __attribute__((ext_vector_type(4)));

// ---------------- fp16x4 pack/unpack ----------------
__device__ __forceinline__ uint2 pack_half4(float4 v) {
    __half2 a = __float22half2_rn(make_float2(v.x, v.y));
    __half2 b = __float22half2_rn(make_float2(v.z, v.w));
    uint2 r;
    r.x = *reinterpret_cast<unsigned int*>(&a);
    r.y = *reinterpret_cast<unsigned int*>(&b);
    return r;
}
__device__ __forceinline__ float4 unpack_half4(uint2 u) {
    __half2 a = *reinterpret_cast<__half2*>(&u.x);
    __half2 b = *reinterpret_cast<__half2*>(&u.y);
    float2 fa = __half22float2(a);
    float2 fb = __half22float2(b);
    return make_float4(fa.x, fa.y, fb.x, fb.y);
}

// ---------------- mask dtype sniff ----------------
__global__ void k_sniff(const unsigned int* __restrict__ w, int nwords, int* __restrict__ flag) {
    __shared__ int sawFloat, sawBig;
    if (threadIdx.x == 0) { sawFloat = 0; sawBig = 0; }
    __syncthreads();
    int f = 0, bg = 0;
    for (int i = threadIdx.x; i < nwords; i += blockDim.x) {
        unsigned int v = w[i];
        if (v == 0u || v == 1u) continue;
        if (v == 0x3F800000u) f = 1; else bg = 1;
    }
    if (f) atomicOr(&sawFloat, 1);
    if (bg) atomicOr(&sawBig, 1);
    __syncthreads();
    if (threadIdx.x == 0) *flag = sawBig ? 1 : (sawFloat ? 2 : 0);
}

__device__ __forceinline__ float mask_val(const void* mask, int mm, long e) {
    if (mm == 1)      return ((const unsigned char*)mask)[e] ? 1.f : 0.f;
    else if (mm == 2) return ((const float*)mask)[e];
    else              return ((const int*)mask)[e] ? 1.f : 0.f;
}

// =====================================================================
// Node encoder via MFMA fp16: h = relu(x[map?] @ w + b), K = 133.
// 128x128 tile, 4 waves, wave = 32 rows x 128 cols.
// A staged [row][40] fp16 (2-way LDS reads); B staged transposed [col][40].
// Fragment maps: A/B lane: (row|col)=l&15, k=(l>>4)*8+j; C/D: col=l&15,
// row=(l>>4)*4+reg (guide §3, m89-verified).
// =====================================================================
template<bool GATHER>
__global__ __launch_bounds__(256)
void k_gemm_enc(const float* __restrict__ x, const int* __restrict__ map, int nrows,
                const float* __restrict__ w, const float* __restrict__ bias,
                float* __restrict__ hout) {
    __shared__ _Float16 a_lds[128][40];
    __shared__ _Float16 w_lds[128][40];   // [col][k]
    __shared__ int m_lds[128];
    const int tid = threadIdx.x;
    const int rbase = blockIdx.x * 128;
    if (GATHER && tid < 128) {
        int row = rbase + tid;
        m_lds[tid] = (row < nrows) ? map[row] : 0;
    }
    const int lane = tid & 63, wv = tid >> 6;
    const int lrow = lane & 15, kgrp = lane >> 4;
    f32x4 acc[2][8] = {};
    for (int kc = 0; kc < 5; ++kc) {
        const int k0 = kc * 32;
        __syncthreads();
        for (int i = tid; i < 128 * 32; i += 256) {
            int r = i >> 5, kk = i & 31;
            int row = rbase + r;
            float v = 0.f;
            if (row < nrows && k0 + kk < FN) {
                int sr = GATHER ? m_lds[r] : row;
                v = x[(size_t)sr * FN + k0 + kk];
            }
            a_lds[r][kk] = (_Float16)v;
        }
        for (int i = tid; i < 32 * 128; i += 256) {
            int kk = i >> 7, col = i & 127;
            float v = (k0 + kk < FN) ? w[(size_t)(k0 + kk) * H + col] : 0.f;
            w_lds[col][kk] = (_Float16)v;
        }
        __syncthreads();
        f16x8 af0 = *reinterpret_cast<const f16x8*>(&a_lds[wv * 32 + lrow][kgrp * 8]);
        f16x8 af1 = *reinterpret_cast<const f16x8*>(&a_lds[wv * 32 + 16 + lrow][kgrp * 8]);
        #pragma unroll
        for (int ct = 0; ct < 8; ++ct) {
            f16x8 bf = *reinterpret_cast<const f16x8*>(&w_lds[ct * 16 + lrow][kgrp * 8]);
            acc[0][ct] = __builtin_amdgcn_mfma_f32_16x16x32_f16(af0, bf, acc[0][ct], 0, 0, 0);
            acc[1][ct] = __builtin_amdgcn_mfma_f32_16x16x32_f16(af1, bf, acc[1][ct], 0, 0, 0);
        }
    }
    float bcol[8];
    #pragma unroll
    for (int ct = 0; ct < 8; ++ct) bcol[ct] = bias[ct * 16 + lrow];
    #pragma unroll
    for (int rt = 0; rt < 2; ++rt) {
        #pragma unroll
        for (int j = 0; j < 4; ++j) {
            int row = rbase + wv * 32 + rt * 16 + kgrp * 4 + j;
            if (row < nrows) {
                float* hp = hout + (size_t)row * H + lrow;
                #pragma unroll
                for (int ct = 0; ct < 8; ++ct)
                    hp[ct * 16] = fmaxf(acc[rt][ct][j] + bcol[ct], 0.f);
            }
        }
    }
}

// =====================================================================
// Edge CSR build
// =====================================================================
template<int MODE>
__global__ __launch_bounds__(256)
void k_hist(const int* __restrict__ dst, const float* __restrict__ edge_weight,
            const int* __restrict__ emap, const void* __restrict__ mask,
            const int* __restrict__ mmode_p, int* __restrict__ deg, int nedges) {
    int e = blockIdx.x * 256 + threadIdx.x;
    if (e >= nedges) return;
    int eo = MODE ? emap[e] : e;
    float w = edge_weight[eo];
    if (MODE) w *= mask_val(mask, *mmode_p, e);
    if (w != 0.f) atomicAdd(&deg[dst[e]], 1);
}

__global__ __launch_bounds__(256)
void k_scan1(const int* __restrict__ deg, int* __restrict__ off, int* __restrict__ bsum, int n) {
    __shared__ int tsum[256];
    const int tid = threadIdx.x;
    const int base = blockIdx.x * 1024;
    int local[4]; int s = 0;
    #pragma unroll
    for (int j = 0; j < 4; ++j) {
        int i = base + tid * 4 + j;
        local[j] = (i < n) ? deg[i] : 0;
        s += local[j];
    }
    tsum[tid] = s;
    __syncthreads();
    for (int d = 1; d < 256; d <<= 1) {
        int v = (tid >= d) ? tsum[tid - d] : 0;
        __syncthreads();
        tsum[tid] += v;
        __syncthreads();
    }
    int excl = tsum[tid] - s;
    #pragma unroll
    for (int j = 0; j < 4; ++j) {
        int i = base + tid * 4 + j;
        if (i < n) off[i] = excl;
        excl += local[j];
    }
    if (tid == 255) bsum[blockIdx.x] = tsum[255];
}

__global__ __launch_bounds__(256)
void k_scan2(int* __restrict__ bsum, int nb) {
    __shared__ int tsum[256];
    const int tid = threadIdx.x;
    int local[4]; int s = 0;
    #pragma unroll
    for (int j = 0; j < 4; ++j) {
        int i = tid * 4 + j;
        local[j] = (i < nb) ? bsum[i] : 0;
        s += local[j];
    }
    tsum[tid] = s;
    __syncthreads();
    for (int d = 1; d < 256; d <<= 1) {
        int v = (tid >= d) ? tsum[tid - d] : 0;
        __syncthreads();
        tsum[tid] += v;
        __syncthreads();
    }
    int excl = tsum[tid] - s;
    #pragma unroll
    for (int j = 0; j < 4; ++j) {
        int i = tid * 4 + j;
        if (i < nb) bsum[i] = excl;
        excl += local[j];
    }
}

__global__ __launch_bounds__(256)
void k_scan3(const int* __restrict__ bsum, int* __restrict__ off, int* __restrict__ cur, int n) {
    int i = blockIdx.x * 256 + threadIdx.x;
    if (i < n) {
        int o = off[i] + bsum[i >> 10];
        off[i] = o;
        cur[i] = o;
    }
}

template<int MODE>
__global__ __launch_bounds__(256)
void k_scatter(const int* __restrict__ src, const int* __restrict__ dst,
               const float* __restrict__ edge_weight,
               const int* __restrict__ emap, const void* __restrict__ mask,
               const int* __restrict__ mmode_p, int* __restrict__ cur,
               int2* __restrict__ epk, int2* __restrict__ epkh,
               int nedges) {
    int e = blockIdx.x * 256 + threadIdx.x;
    if (e >= nedges) return;
    int eo = MODE ? emap[e] : e;
    float w = edge_weight[eo];
    if (MODE) w *= mask_val(mask, *mmode_p, e);
    if (w != 0.f) {
        int pos = atomicAdd(&cur[dst[e]], 1);
        int wb = __float_as_int(w);
        epk[pos]  = make_int2(src[e], wb);
        epkh[pos] = make_int2(eo, wb);
    }
}

// =====================================================================
// Fused t=0 walk (packed fp32 eh math; fp16 outputs)
// =====================================================================
__global__ __launch_bounds__(256)
void k_msg_eh(const int* __restrict__ off, const int* __restrict__ deg,
              const int2* __restrict__ epk, const int2* __restrict__ epkh,
              const float* __restrict__ edge_attr,
              const float* __restrict__ w_edge, const float* __restrict__ b_edge,
              const float* __restrict__ h,
              __half* __restrict__ agg, __half* __restrict__ aggeh, int nnodes) {
    __shared__ float we_lds[FE * H];
    __shared__ float be_lds[H];
    for (int i = threadIdx.x; i < FE * H; i += 256) we_lds[i] = w_edge[i];
    if (threadIdx.x < H) be_lds[threadIdx.x] = b_edge[threadIdx.x];
    __syncthreads();
    const int hw = threadIdx.x >> 5;
    const int ln = threadIdx.x & 31;
    const int c  = ln * 4;
    int v = blockIdx.x * 8 + hw;
    if (v >= nnodes) return;
    v2f acc0 = {0.f, 0.f}, acc1 = {0.f, 0.f};
    v2f aeh0 = {0.f, 0.f}, aeh1 = {0.f, 0.f};
    const int o = off[v], d = deg[v];
    const float4 bev = *reinterpret_cast<const float4*>(be_lds + c);
    const v2f bev0 = {bev.x, bev.y}, bev1 = {bev.z, bev.w};
    for (int jb = 0; jb < d; jb += 32) {
        const int nn = min(32, d - jb);
        int2 m1 = make_int2(0, 0), m2 = make_int2(0, 0);
        if (ln < nn) { m1 = epk[o + jb + ln]; m2 = epkh[o + jb + ln]; }
        const int msrc = m1.x;
        const int meo  = m2.x;
        const float mw = __int_as_float(m1.y);
        for (int q = 0; q < nn; q += 2) {
            int   s0 = __shfl(msrc, q, 32);
            int   e0 = __shfl(meo,  q, 32);
            float w0 = __shfl(mw,   q, 32);
            int   s1 = __shfl(msrc, q + 1, 32);
            int   e1 = __shfl(meo,  q + 1, 32);
            float w1 = __shfl(mw,   q + 1, 32);
            if (q + 1 >= nn) { s1 = s0; e1 = e0; w1 = 0.f; }
            float4 hv0 = *reinterpret_cast<const float4*>(h + (size_t)s0 * H + c);
            float4 hv1 = *reinterpret_cast<const float4*>(h + (size_t)s1 * H + c);
            float a0 = (ln < FE) ? edge_attr[(size_t)e0 * FE + ln] : 0.f;
            float a1 = (ln < FE) ? edge_attr[(size_t)e1 * FE + ln] : 0.f;
            v2f eh00 = bev0, eh01 = bev1, eh10 = bev0, eh11 = bev1;
            #pragma unroll
            for (int k = 0; k < FE; ++k) {
                float f0 = __shfl(a0, k, 32);
                float f1 = __shfl(a1, k, 32);
                float4 wv = *reinterpret_cast<const float4*>(we_lds + k * H + c);
                v2f wva = {wv.x, wv.y}, wvb = {wv.z, wv.w};
                v2f f0v = {f0, f0}, f1v = {f1, f1};
                eh00 += f0v * wva; eh01 += f0v * wvb;
                eh10 += f1v * wva; eh11 += f1v * wvb;
            }
            v2f r00 = {w0 * fmaxf(eh00.x, 0.f), w0 * fmaxf(eh00.y, 0.f)};
            v2f r01 = {w0 * fmaxf(eh01.x, 0.f), w0 * fmaxf(eh01.y, 0.f)};
            v2f r10 = {w1 * fmaxf(eh10.x, 0.f), w1 * fmaxf(eh10.y, 0.f)};
            v2f r11 = {w1 * fmaxf(eh11.x, 0.f), w1 * fmaxf(eh11.y, 0.f)};
            aeh0 += r00 + r10; aeh1 += r01 + r11;
            v2f w0v = {w0, w0}, w1v = {w1, w1};
            acc0 += w0v * (v2f){hv0.x, hv0.y} + w1v * (v2f){hv1.x, hv1.y} + r00 + r10;
            acc1 += w0v * (v2f){hv0.z, hv0.w} + w1v * (v2f){hv1.z, hv1.w} + r01 + r11;
        }
    }
    *reinterpret_cast<uint2*>(agg   + (size_t)v * H + c) = pack_half4(make_float4(acc0.x, acc0.y, acc1.x, acc1.y));
    *reinterpret_cast<uint2*>(aggeh + (size_t)v * H + c) = pack_half4(make_float4(aeh0.x, aeh0.y, aeh1.x, aeh1.y));
}

// =====================================================================
// CSR message pass (t=1,2): agg = aggeh + sum w*h[src]; packed accumulate
// =====================================================================
__global__ __launch_bounds__(256)
void k_msg_csr(const int* __restrict__ off, const int* __restrict__ deg,
               const int2* __restrict__ epk, const __half* __restrict__ aggeh,
               const float* __restrict__ h, __half* __restrict__ agg, int nnodes) {
    const int hw = threadIdx.x >> 5;
    const int ln = threadIdx.x & 31;
    const int c  = ln * 4;
    int v = blockIdx.x * 8 + hw;
    if (v >= nnodes) return;
    float4 a0 = unpack_half4(*reinterpret_cast<const uint2*>(aggeh + (size_t)v * H + c));
    v2f acc0 = {a0.x, a0.y}, acc1 = {a0.z, a0.w};
    const int o = off[v], d = deg[v];
    for (int jb = 0; jb < d; jb += 32) {
        const int nn = min(32, d - jb);
        int2 meta = make_int2(0, 0);
        if (ln < nn) meta = epk[o + jb + ln];
        const int ms = meta.x;
        const float mw = __int_as_float(meta.y);
        for (int q = 0; q < nn; q += 4) {
            #pragma unroll
            for (int u = 0; u < 4; ++u) {
                int qq = q + u;
                int   s = __shfl(ms, qq, 32);
                float w = __shfl(mw, qq, 32);
                if (qq >= nn) { s = 0; w = 0.f; }
                float4 hv = *reinterpret_cast<const float4*>(h + (size_t)s * H + c);
                v2f wv = {w, w};
                acc0 += wv * (v2f){hv.x, hv.y};
                acc1 += wv * (v2f){hv.z, hv.w};
            }
        }
    }
    *reinterpret_cast<uint2*>(agg + (size_t)v * H + c) = pack_half4(make_float4(acc0.x, acc0.y, acc1.x, acc1.y));
}

// =====================================================================
// h = relu(h + agg @ w_mp + b_mp), in place; agg fp16; scalar microkernel.
// (HBM-bound at ~5 TB/s; MFMA would not help here.)
// =====================================================================
__global__ __launch_bounds__(256)
void k_gemm_update(const __half* __restrict__ agg, int nrows,
                   const float* __restrict__ w, const float* __restrict__ bias,
                   float* __restrict__ h) {
    __shared__ float w_lds[32][H];
    __shared__ float a_lds[32][APAD];
    const int tid = threadIdx.x;
    const int rbase = blockIdx.x * 128;
    const int tx = tid & 15, ty = tid >> 4;
    float acc[8][8] = {};
    for (int kc = 0; kc < 4; ++kc) {
        const int k0 = kc * 32;
        __syncthreads();
        for (int i = tid; i < 1024; i += 256) {
            int kk = i >> 5, c4 = i & 31;
            *reinterpret_cast<float4*>(&w_lds[kk][c4 * 4]) =
                reinterpret_cast<const float4*>(w + (size_t)(k0 + kk) * H)[c4];
        }
        for (int i = tid; i < 1024; i += 256) {
            int r = i >> 3, f = i & 7;
            int row = rbase + r;
            float4 v = make_float4(0.f, 0.f, 0.f, 0.f);
            if (row < nrows)
                v = unpack_half4(reinterpret_cast<const uint2*>(agg + (size_t)row * H + k0)[f]);
            a_lds[f * 4 + 0][r] = v.x;
            a_lds[f * 4 + 1][r] = v.y;
            a_lds[f * 4 + 2][r] = v.z;
            a_lds[f * 4 + 3][r] = v.w;
        }
        __syncthreads();
        #pragma unroll 4
        for (int k = 0; k < 32; ++k) {
            float4 a0 = *reinterpret_cast<const float4*>(&a_lds[k][ty * 8]);
            float4 a1 = *reinterpret_cast<const float4*>(&a_lds[k][ty * 8 + 4]);
            float4 w0 = *reinterpret_cast<const float4*>(&w_lds[k][tx * 4]);
            float4 w1 = *reinterpret_cast<const float4*>(&w_lds[k][64 + tx * 4]);
            float aa[8] = {a0.x, a0.y, a0.z, a0.w, a1.x, a1.y, a1.z, a1.w};
            float ww[8] = {w0.x, w0.y, w0.z, w0.w, w1.x, w1.y, w1.z, w1.w};
            #pragma unroll
            for (int i2 = 0; i2 < 8; ++i2)
                #pragma unroll
                for (int j = 0; j < 8; ++j)
                    acc[i2][j] += aa[i2] * ww[j];
        }
    }
    float4 b0 = *reinterpret_cast<const float4*>(bias + tx * 4);
    float4 b1 = *reinterpret_cast<const float4*>(bias + 64 + tx * 4);
    float bb[8] = {b0.x, b0.y, b0.z, b0.w, b1.x, b1.y, b1.z, b1.w};
    #pragma unroll
    for (int i2 = 0; i2 < 8; ++i2) {
        int row = rbase + ty * 8 + i2;
        if (row < nrows) {
            float* hp = h + (size_t)row * H + tx * 4;
            float4 h0 = *reinterpret_cast<const float4*>(hp);
            float4 h1 = *reinterpret_cast<const float4*>(hp + 64);
            float4 o0, o1;
            o0.x = fmaxf(h0.x + acc[i2][0] + bb[0], 0.f); o0.y = fmaxf(h0.y + acc[i2][1] + bb[1], 0.f);
            o0.z = fmaxf(h0.z + acc[i2][2] + bb[2], 0.f); o0.w = fmaxf(h0.w + acc[i2][3] + bb[3], 0.f);
            o1.x = fmaxf(h1.x + acc[i2][4] + bb[4], 0.f); o1.y = fmaxf(h1.y + acc[i2][5] + bb[5], 0.f);
            o1.z = fmaxf(h1.z + acc[i2][6] + bb[6], 0.f); o1.w = fmaxf(h1.w + acc[i2][7] + bb[7], 0.f);
            *reinterpret_cast<float4*>(hp)      = o0;
            *reinterpret_cast<float4*>(hp + 64) = o1;
        }
    }
}

// =====================================================================
// Group-CSR pool
// =====================================================================
__global__ __launch_bounds__(256)
void k_ghist(const int* __restrict__ rowmap, const int* __restrict__ batch,
             int* __restrict__ deg_g, int nrows) {
    int r = blockIdx.x * 256 + threadIdx.x;
    if (r < nrows) atomicAdd(&deg_g[batch[rowmap[r]]], 1);
}

__global__ __launch_bounds__(256)
void k_gscan(const int* __restrict__ deg, int* __restrict__ off, int* __restrict__ cur) {
    __shared__ int tsum[256];
    const int tid = threadIdx.x;
    int local[4]; int s = 0;
    #pragma unroll
    for (int j = 0; j < 4; ++j) { local[j] = deg[tid * 4 + j]; s += local[j]; }
    tsum[tid] = s;
    __syncthreads();
    for (int d = 1; d < 256; d <<= 1) {
        int v = (tid >= d) ? tsum[tid - d] : 0;
        __syncthreads();
        tsum[tid] += v;
        __syncthreads();
    }
    int excl = tsum[tid] - s;
    #pragma unroll
    for (int j = 0; j < 4; ++j) {
        off[tid * 4 + j] = excl;
        cur[tid * 4 + j] = excl;
        excl += local[j];
    }
}

template<bool GATHER>
__global__ __launch_bounds__(256)
void k_gscatter(const int* __restrict__ rowmap, const int* __restrict__ batch,
                const float* __restrict__ nodew, int* __restrict__ cur,
                int* __restrict__ prow, float* __restrict__ pnw, int nrows) {
    int r = blockIdx.x * 256 + threadIdx.x;
    if (r >= nrows) return;
    int oid = rowmap[r];
    int g = batch[oid];
    int pos = atomicAdd(&cur[g], 1);
    prow[pos] = GATHER ? oid : r;
    pnw[pos]  = nodew[oid];
}

__global__ __launch_bounds__(256)
void k_pool(const int* __restrict__ off_g, const int* __restrict__ deg_g,
            const int* __restrict__ prow, const float* __restrict__ pnw,
            const float* __restrict__ h,
            const float* __restrict__ w, const float* __restrict__ bias,
            float* __restrict__ outp) {
    __shared__ float s_lds[4][H];
    __shared__ float ssum[H];
    __shared__ float r_lds[2][H];
    __shared__ float cg_lds[4];
    const int g = blockIdx.x;
    const int o = off_g[g], cnt = deg_g[g];
    const int wv = threadIdx.x >> 6, lane = threadIdx.x & 63;
    float ax = 0.f, ay = 0.f, cg = 0.f;
    for (int i = wv; i < cnt; i += 4) {
        int hrow = prow[o + i];
        float nw = pnw[o + i];
        float2 v = *reinterpret_cast<const float2*>(h + (size_t)hrow * H + lane * 2);
        ax += nw * v.x; ay += nw * v.y; cg += nw;
    }
    s_lds[wv][lane * 2]     = ax;
    s_lds[wv][lane * 2 + 1] = ay;
    if (lane == 0) cg_lds[wv] = cg;
    __syncthreads();
    if (threadIdx.x < H)
        ssum[threadIdx.x] = s_lds[0][threadIdx.x] + s_lds[1][threadIdx.x]
                          + s_lds[2][threadIdx.x] + s_lds[3][threadIdx.x];
    __syncthreads();
    const int c = threadIdx.x & 127, kh = threadIdx.x >> 7;
    float p = 0.f;
    #pragma unroll 8
    for (int k = 0; k < 64; ++k)
        p += ssum[kh * 64 + k] * w[(size_t)(kh * 64 + k) * H + c];
    r_lds[kh][c] = p;
    __syncthreads();
    if (threadIdx.x < H) {
        float cga = cg_lds[0] + cg_lds[1] + cg_lds[2] + cg_lds[3];
        float val = r_lds[0][c] + r_lds[1][c] + bias[c] * cga;
        outp[(size_t)g * H + c] = val / fmaxf((float)cnt, 1.f);
    }
}

extern "C" void kernel_launch(void* const* d_in, const int* in_sizes, int n_in,
                              void* d_out, int out_size, void* d_ws, size_t ws_size,
                              hipStream_t stream) {
    (void)n_in; (void)out_size; (void)ws_size;
    const float* x           = (const float*)d_in[0];
    const float* node_weight = (const float*)d_in[1];
    const int*   edge_index  = (const int*)d_in[2];
    const float* edge_attr   = (const float*)d_in[3];
    const float* edge_weight = (const float*)d_in[4];
    const int*   batch       = (const int*)d_in[5];
    const int*   cnm         = (const int*)d_in[6];
    const int*   tnm         = (const int*)d_in[7];
    const int*   csub        = (const int*)d_in[8];
    const int*   sem         = (const int*)d_in[9];
    const void*  cmask       = d_in[10];

    const float* ctx_w_node = (const float*)d_in[11];
    const float* ctx_b_node = (const float*)d_in[12];
    const float* ctx_w_edge = (const float*)d_in[13];
    const float* ctx_b_edge = (const float*)d_in[14];
    const float* ctx_w_mp   = (const float*)d_in[15];
    const float* ctx_b_mp   = (const float*)d_in[16];
    const float* ctx_w_out  = (const float*)d_in[17];
    const float* ctx_b_out  = (const float*)d_in[18];
    const float* tgt_w_node = (const float*)d_in[19];
    const float* tgt_b_node = (const float*)d_in[20];
    const float* tgt_w_edge = (const float*)d_in[21];
    const float* tgt_b_edge = (const float*)d_in[22];
    const float* tgt_w_mp   = (const float*)d_in[23];
    const float* tgt_b_mp   = (const float*)d_in[24];
    const float* tgt_w_out  = (const float*)d_in[25];
    const float* tgt_b_out  = (const float*)d_in[26];

    const int N  = in_sizes[1];
    const int E  = in_sizes[4];
    const int NC = in_sizes[6];
    const int NT = in_sizes[7];
    const int ES = in_sizes[9];
    const int NMAX = (NT > NC) ? NT : NC;

    float* out = (float*)d_out;

    // ---------------- workspace layout ----------------
    char* ws = (char*)d_ws;
    float*  h     = (float*)ws;  ws += (size_t)N * H * sizeof(float);
    __half* agg   = (__half*)ws; ws += (size_t)N * H * sizeof(__half);
    __half* aggeh = (__half*)ws; ws += (size_t)N * H * sizeof(__half);
    int2*  epk    = (int2*)ws;   ws += (size_t)E * sizeof(int2);
    int2*  epkh   = (int2*)ws;   ws += (size_t)E * sizeof(int2);
    int*   deg    = (int*)ws;    ws += (size_t)N * sizeof(int);
    int*   off    = (int*)ws;    ws += (size_t)N * sizeof(int);
    int*   cur    = (int*)ws;    ws += (size_t)N * sizeof(int);
    int*   bsum   = (int*)ws;    ws += 1024 * sizeof(int);
    int*   deg_g  = (int*)ws;    ws += NG * sizeof(int);
    int*   off_g  = (int*)ws;    ws += NG * sizeof(int);
    int*   cur_g  = (int*)ws;    ws += NG * sizeof(int);
    int*   prow   = (int*)ws;    ws += (size_t)NMAX * sizeof(int);
    float* pnw    = (float*)ws;  ws += (size_t)NMAX * sizeof(float);
    int*   flag   = (int*)ws;    ws += sizeof(int);

    int nwords = ES / 4; if (nwords > 8192) nwords = 8192;
    k_sniff<<<1, 256, 0, stream>>>((const unsigned int*)cmask, nwords, flag);

    // ================= FULL graph pass (tgt params) =================
    {
        const int* fsrc = edge_index;
        const int* fdst = edge_index + E;
        hipMemsetAsync(deg, 0, (size_t)N * sizeof(int), stream);
        int egrid = (E + 255) / 256;
        k_hist<0><<<egrid, 256, 0, stream>>>(fdst, edge_weight, nullptr, nullptr, nullptr, deg, E);
        int nb1 = (N + 1023) / 1024;
        k_scan1<<<nb1, 256, 0, stream>>>(deg, off, bsum, N);
        k_scan2<<<1, 256, 0, stream>>>(bsum, nb1);
        k_scan3<<<(N + 255) / 256, 256, 0, stream>>>(bsum, off, cur, N);
        k_scatter<0><<<egrid, 256, 0, stream>>>(fsrc, fdst, edge_weight, nullptr, nullptr, nullptr,
                                                cur, epk, epkh, E);
        k_gemm_enc<false><<<(N + 127) / 128, 256, 0, stream>>>(x, nullptr, N, tgt_w_node, tgt_b_node, h);
        k_msg_eh<<<(N + 7) / 8, 256, 0, stream>>>(off, deg, epk, epkh, edge_attr,
                                                  tgt_w_edge, tgt_b_edge, h, agg, aggeh, N);
        k_gemm_update<<<(N + 127) / 128, 256, 0, stream>>>(agg, N, tgt_w_mp, tgt_b_mp, h);
        for (int t = 1; t < 3; ++t) {
            k_msg_csr<<<(N + 7) / 8, 256, 0, stream>>>(off, deg, epk, aggeh, h, agg, N);
            k_gemm_update<<<(N + 127) / 128, 256, 0, stream>>>(agg, N,
                                                               tgt_w_mp + t * H * H, tgt_b_mp + t * H, h);
        }
        hipMemsetAsync(deg_g, 0, NG * sizeof(int), stream);
        k_ghist<<<(NT + 255) / 256, 256, 0, stream>>>(tnm, batch, deg_g, NT);
        k_gscan<<<1, 256, 0, stream>>>(deg_g, off_g, cur_g);
        k_gscatter<true><<<(NT + 255) / 256, 256, 0, stream>>>(tnm, batch, node_weight, cur_g, prow, pnw, NT);
        k_pool<<<NG, 256, 0, stream>>>(off_g, deg_g, prow, pnw, h, tgt_w_out, tgt_b_out,
                                       out + (size_t)NG * H);
    }

    // ================= CTX subgraph pass (ctx params) =================
    {
        const int* csrc = csub;
        const int* cdst = csub + ES;
        hipMemsetAsync(deg, 0, (size_t)NC * sizeof(int), stream);
        int egrid = (ES + 255) / 256;
        k_hist<1><<<egrid, 256, 0, stream>>>(cdst, edge_weight, sem, cmask, flag, deg, ES);
        int nb1 = (NC + 1023) / 1024;
        k_scan1<<<nb1, 256, 0, stream>>>(deg, off, bsum, NC);
        k_scan2<<<1, 256, 0, stream>>>(bsum, nb1);
        k_scan3<<<(NC + 255) / 256, 256, 0, stream>>>(bsum, off, cur, NC);
        k_scatter<1><<<egrid, 256, 0, stream>>>(csrc, cdst, edge_weight, sem, cmask, flag,
                                                cur, epk, epkh, ES);
        k_gemm_enc<true><<<(NC + 127) / 128, 256, 0, stream>>>(x, cnm, NC, ctx_w_node, ctx_b_node, h);
        k_msg_eh<<<(NC + 7) / 8, 256, 0, stream>>>(off, deg, epk, epkh, edge_attr,
                                                   ctx_w_edge, ctx_b_edge, h, agg, aggeh, NC);
        k_gemm_update<<<(NC + 127) / 128, 256, 0, stream>>>(agg, NC, ctx_w_mp, ctx_b_mp, h);
        for (int t = 1; t < 3; ++t) {
            k_msg_csr<<<(NC + 7) / 8, 256, 0, stream>>>(off, deg, epk, aggeh, h, agg, NC);
            k_gemm_update<<<(NC + 127) / 128, 256, 0, stream>>>(agg, NC,
                                                                ctx_w_mp + t * H * H, ctx_b_mp + t * H, h);
        }
        hipMemsetAsync(deg_g, 0, NG * sizeof(int), stream);
        k_ghist<<<(NC + 255) / 256, 256, 0, stream>>>(cnm, batch, deg_g, NC);
        k_gscan<<<1, 256, 0, stream>>>(deg_g, off_g, cur_g);
        k_gscatter<false><<<(NC + 255) / 256, 256, 0, stream>>>(cnm, batch, node_weight, cur_g, prow, pnw, NC);
        k_pool<<<NG, 256, 0, stream>>>(off_g, deg_g, prow, pnw, h, ctx_w_out, ctx_b_out, out);
    }
}

// Round 17
// 1498.659 us; speedup vs baseline: 1.0330x; 1.0330x over previous
//
#include <hip/hip_runtime.h>
#include <hip/hip_fp16.h>
#include <stdint.h>

#define H 128
#define FN 133
#define FE 14
#define NG 1024
#define APAD 133

typedef float v2f __attribute__((ext_vector_type(2)));

// ---------------- fp16x4 pack/unpack ----------------
__device__ __forceinline__ uint2 pack_half4(float4 v) {
    __half2 a = __float22half2_rn(make_float2(v.x, v.y));
    __half2 b = __float22half2_rn(make_float2(v.z, v.w));
    uint2 r;
    r.x = *reinterpret_cast<unsigned int*>(&a);
    r.y = *reinterpret_cast<unsigned int*>(&b);
    return r;
}
__device__ __forceinline__ float4 unpack_half4(uint2 u) {
    __half2 a = *reinterpret_cast<__half2*>(&u.x);
    __half2 b = *reinterpret_cast<__half2*>(&u.y);
    float2 fa = __half22float2(a);
    float2 fb = __half22float2(b);
    return make_float4(fa.x, fa.y, fb.x, fb.y);
}

// ---------------- mask dtype sniff ----------------
__global__ void k_sniff(const unsigned int* __restrict__ w, int nwords, int* __restrict__ flag) {
    __shared__ int sawFloat, sawBig;
    if (threadIdx.x == 0) { sawFloat = 0; sawBig = 0; }
    __syncthreads();
    int f = 0, bg = 0;
    for (int i = threadIdx.x; i < nwords; i += blockDim.x) {
        unsigned int v = w[i];
        if (v == 0u || v == 1u) continue;
        if (v == 0x3F800000u) f = 1; else bg = 1;
    }
    if (f) atomicOr(&sawFloat, 1);
    if (bg) atomicOr(&sawBig, 1);
    __syncthreads();
    if (threadIdx.x == 0) *flag = sawBig ? 1 : (sawFloat ? 2 : 0);
}

__device__ __forceinline__ float mask_val(const void* mask, int mm, long e) {
    if (mm == 1)      return ((const unsigned char*)mask)[e] ? 1.f : 0.f;
    else if (mm == 2) return ((const float*)mask)[e];
    else              return ((const int*)mask)[e] ? 1.f : 0.f;
}

// =====================================================================
// Node encoder: h = relu(x[map?] @ w + b), K = 133 (5 zero-padded chunks)
// Scalar 8x8 microkernel, 52 VGPR, col-split w-reads.
// =====================================================================
template<bool GATHER>
__global__ __launch_bounds__(256)
void k_gemm_enc(const float* __restrict__ x, const int* __restrict__ map, int nrows,
                const float* __restrict__ w, const float* __restrict__ bias,
                float* __restrict__ hout) {
    __shared__ float w_lds[32][H];
    __shared__ float a_lds[32][APAD];
    __shared__ int   m_lds[128];
    const int tid = threadIdx.x;
    const int rbase = blockIdx.x * 128;
    if (GATHER && tid < 128) {
        int row = rbase + tid;
        m_lds[tid] = (row < nrows) ? map[row] : 0;
    }
    const int tx = tid & 15, ty = tid >> 4;
    float acc[8][8] = {};
    for (int kc = 0; kc < 5; ++kc) {
        const int k0 = kc * 32;
        __syncthreads();
        for (int i = tid; i < 32 * 32; i += 256) {
            int kk = i >> 5, c4 = i & 31;
            float4 v = make_float4(0.f, 0.f, 0.f, 0.f);
            if (k0 + kk < FN)
                v = reinterpret_cast<const float4*>(w + (size_t)(k0 + kk) * H)[c4];
            *reinterpret_cast<float4*>(&w_lds[kk][c4 * 4]) = v;
        }
        for (int i = tid; i < 128 * 32; i += 256) {
            int r = i >> 5, kk = i & 31;
            int row = rbase + r;
            float v = 0.f;
            if (row < nrows && k0 + kk < FN) {
                int sr = GATHER ? m_lds[r] : row;
                v = x[(size_t)sr * FN + k0 + kk];
            }
            a_lds[kk][r] = v;
        }
        __syncthreads();
        #pragma unroll 4
        for (int k = 0; k < 32; ++k) {
            float4 a0 = *reinterpret_cast<const float4*>(&a_lds[k][ty * 8]);
            float4 a1 = *reinterpret_cast<const float4*>(&a_lds[k][ty * 8 + 4]);
            float4 w0 = *reinterpret_cast<const float4*>(&w_lds[k][tx * 4]);
            float4 w1 = *reinterpret_cast<const float4*>(&w_lds[k][64 + tx * 4]);
            float aa[8] = {a0.x, a0.y, a0.z, a0.w, a1.x, a1.y, a1.z, a1.w};
            float ww[8] = {w0.x, w0.y, w0.z, w0.w, w1.x, w1.y, w1.z, w1.w};
            #pragma unroll
            for (int i2 = 0; i2 < 8; ++i2)
                #pragma unroll
                for (int j = 0; j < 8; ++j)
                    acc[i2][j] += aa[i2] * ww[j];
        }
    }
    float4 b0 = *reinterpret_cast<const float4*>(bias + tx * 4);
    float4 b1 = *reinterpret_cast<const float4*>(bias + 64 + tx * 4);
    float bb[8] = {b0.x, b0.y, b0.z, b0.w, b1.x, b1.y, b1.z, b1.w};
    #pragma unroll
    for (int i2 = 0; i2 < 8; ++i2) {
        int row = rbase + ty * 8 + i2;
        if (row < nrows) {
            float4 o0, o1;
            o0.x = fmaxf(acc[i2][0] + bb[0], 0.f); o0.y = fmaxf(acc[i2][1] + bb[1], 0.f);
            o0.z = fmaxf(acc[i2][2] + bb[2], 0.f); o0.w = fmaxf(acc[i2][3] + bb[3], 0.f);
            o1.x = fmaxf(acc[i2][4] + bb[4], 0.f); o1.y = fmaxf(acc[i2][5] + bb[5], 0.f);
            o1.z = fmaxf(acc[i2][6] + bb[6], 0.f); o1.w = fmaxf(acc[i2][7] + bb[7], 0.f);
            float* hp = hout + (size_t)row * H + tx * 4;
            *reinterpret_cast<float4*>(hp)      = o0;
            *reinterpret_cast<float4*>(hp + 64) = o1;
        }
    }
}

// =====================================================================
// Edge CSR build
// =====================================================================
template<int MODE>
__global__ __launch_bounds__(256)
void k_hist(const int* __restrict__ dst, const float* __restrict__ edge_weight,
            const int* __restrict__ emap, const void* __restrict__ mask,
            const int* __restrict__ mmode_p, int* __restrict__ deg, int nedges) {
    int e = blockIdx.x * 256 + threadIdx.x;
    if (e >= nedges) return;
    int eo = MODE ? emap[e] : e;
    float w = edge_weight[eo];
    if (MODE) w *= mask_val(mask, *mmode_p, e);
    if (w != 0.f) atomicAdd(&deg[dst[e]], 1);
}

__global__ __launch_bounds__(256)
void k_scan1(const int* __restrict__ deg, int* __restrict__ off, int* __restrict__ bsum, int n) {
    __shared__ int tsum[256];
    const int tid = threadIdx.x;
    const int base = blockIdx.x * 1024;
    int local[4]; int s = 0;
    #pragma unroll
    for (int j = 0; j < 4; ++j) {
        int i = base + tid * 4 + j;
        local[j] = (i < n) ? deg[i] : 0;
        s += local[j];
    }
    tsum[tid] = s;
    __syncthreads();
    for (int d = 1; d < 256; d <<= 1) {
        int v = (tid >= d) ? tsum[tid - d] : 0;
        __syncthreads();
        tsum[tid] += v;
        __syncthreads();
    }
    int excl = tsum[tid] - s;
    #pragma unroll
    for (int j = 0; j < 4; ++j) {
        int i = base + tid * 4 + j;
        if (i < n) off[i] = excl;
        excl += local[j];
    }
    if (tid == 255) bsum[blockIdx.x] = tsum[255];
}

__global__ __launch_bounds__(256)
void k_scan2(int* __restrict__ bsum, int nb) {
    __shared__ int tsum[256];
    const int tid = threadIdx.x;
    int local[4]; int s = 0;
    #pragma unroll
    for (int j = 0; j < 4; ++j) {
        int i = tid * 4 + j;
        local[j] = (i < nb) ? bsum[i] : 0;
        s += local[j];
    }
    tsum[tid] = s;
    __syncthreads();
    for (int d = 1; d < 256; d <<= 1) {
        int v = (tid >= d) ? tsum[tid - d] : 0;
        __syncthreads();
        tsum[tid] += v;
        __syncthreads();
    }
    int excl = tsum[tid] - s;
    #pragma unroll
    for (int j = 0; j < 4; ++j) {
        int i = tid * 4 + j;
        if (i < nb) bsum[i] = excl;
        excl += local[j];
    }
}

__global__ __launch_bounds__(256)
void k_scan3(const int* __restrict__ bsum, int* __restrict__ off, int* __restrict__ cur, int n) {
    int i = blockIdx.x * 256 + threadIdx.x;
    if (i < n) {
        int o = off[i] + bsum[i >> 10];
        off[i] = o;
        cur[i] = o;
    }
}

template<int MODE>
__global__ __launch_bounds__(256)
void k_scatter(const int* __restrict__ src, const int* __restrict__ dst,
               const float* __restrict__ edge_weight,
               const int* __restrict__ emap, const void* __restrict__ mask,
               const int* __restrict__ mmode_p, int* __restrict__ cur,
               int2* __restrict__ epk, int2* __restrict__ epkh,
               int nedges) {
    int e = blockIdx.x * 256 + threadIdx.x;
    if (e >= nedges) return;
    int eo = MODE ? emap[e] : e;
    float w = edge_weight[eo];
    if (MODE) w *= mask_val(mask, *mmode_p, e);
    if (w != 0.f) {
        int pos = atomicAdd(&cur[dst[e]], 1);
        int wb = __float_as_int(w);
        epk[pos]  = make_int2(src[e], wb);
        epkh[pos] = make_int2(eo, wb);
    }
}

// =====================================================================
// Needed-node mark + compact (for last full-graph MP step)
// =====================================================================
__global__ __launch_bounds__(256)
void k_mark(const int* __restrict__ rowmap, int* __restrict__ nflag, int nrows) {
    int r = blockIdx.x * 256 + threadIdx.x;
    if (r < nrows) nflag[rowmap[r]] = 1;
}

__global__ __launch_bounds__(256)
void k_compact(const int* __restrict__ nflag, int* __restrict__ list,
               int* __restrict__ cnt, int n) {
    int i = blockIdx.x * 256 + threadIdx.x;
    bool p = (i < n) && (nflag[i] != 0);
    unsigned long long m = __ballot(p);
    int lane = threadIdx.x & 63;
    int wcount = __popcll(m);
    int base = 0;
    if (lane == 0 && wcount) base = atomicAdd(cnt, wcount);
    base = __shfl(base, 0, 64);
    if (p) {
        int pos = base + (int)__popcll(m & ((1ull << lane) - 1ull));
        list[pos] = i;
    }
}

// =====================================================================
// Fused t=0 walk (packed fp32 eh math; fp16 outputs)
// =====================================================================
__global__ __launch_bounds__(256)
void k_msg_eh(const int* __restrict__ off, const int* __restrict__ deg,
              const int2* __restrict__ epk, const int2* __restrict__ epkh,
              const float* __restrict__ edge_attr,
              const float* __restrict__ w_edge, const float* __restrict__ b_edge,
              const float* __restrict__ h,
              __half* __restrict__ agg, __half* __restrict__ aggeh, int nnodes) {
    __shared__ float we_lds[FE * H];
    __shared__ float be_lds[H];
    for (int i = threadIdx.x; i < FE * H; i += 256) we_lds[i] = w_edge[i];
    if (threadIdx.x < H) be_lds[threadIdx.x] = b_edge[threadIdx.x];
    __syncthreads();
    const int hw = threadIdx.x >> 5;
    const int ln = threadIdx.x & 31;
    const int c  = ln * 4;
    int v = blockIdx.x * 8 + hw;
    if (v >= nnodes) return;
    v2f acc0 = {0.f, 0.f}, acc1 = {0.f, 0.f};
    v2f aeh0 = {0.f, 0.f}, aeh1 = {0.f, 0.f};
    const int o = off[v], d = deg[v];
    const float4 bev = *reinterpret_cast<const float4*>(be_lds + c);
    const v2f bev0 = {bev.x, bev.y}, bev1 = {bev.z, bev.w};
    for (int jb = 0; jb < d; jb += 32) {
        const int nn = min(32, d - jb);
        int2 m1 = make_int2(0, 0), m2 = make_int2(0, 0);
        if (ln < nn) { m1 = epk[o + jb + ln]; m2 = epkh[o + jb + ln]; }
        const int msrc = m1.x;
        const int meo  = m2.x;
        const float mw = __int_as_float(m1.y);
        for (int q = 0; q < nn; q += 2) {
            int   s0 = __shfl(msrc, q, 32);
            int   e0 = __shfl(meo,  q, 32);
            float w0 = __shfl(mw,   q, 32);
            int   s1 = __shfl(msrc, q + 1, 32);
            int   e1 = __shfl(meo,  q + 1, 32);
            float w1 = __shfl(mw,   q + 1, 32);
            if (q + 1 >= nn) { s1 = s0; e1 = e0; w1 = 0.f; }
            float4 hv0 = *reinterpret_cast<const float4*>(h + (size_t)s0 * H + c);
            float4 hv1 = *reinterpret_cast<const float4*>(h + (size_t)s1 * H + c);
            float a0 = (ln < FE) ? edge_attr[(size_t)e0 * FE + ln] : 0.f;
            float a1 = (ln < FE) ? edge_attr[(size_t)e1 * FE + ln] : 0.f;
            v2f eh00 = bev0, eh01 = bev1, eh10 = bev0, eh11 = bev1;
            #pragma unroll
            for (int k = 0; k < FE; ++k) {
                float f0 = __shfl(a0, k, 32);
                float f1 = __shfl(a1, k, 32);
                float4 wv = *reinterpret_cast<const float4*>(we_lds + k * H + c);
                v2f wva = {wv.x, wv.y}, wvb = {wv.z, wv.w};
                v2f f0v = {f0, f0}, f1v = {f1, f1};
                eh00 += f0v * wva; eh01 += f0v * wvb;
                eh10 += f1v * wva; eh11 += f1v * wvb;
            }
            v2f r00 = {w0 * fmaxf(eh00.x, 0.f), w0 * fmaxf(eh00.y, 0.f)};
            v2f r01 = {w0 * fmaxf(eh01.x, 0.f), w0 * fmaxf(eh01.y, 0.f)};
            v2f r10 = {w1 * fmaxf(eh10.x, 0.f), w1 * fmaxf(eh10.y, 0.f)};
            v2f r11 = {w1 * fmaxf(eh11.x, 0.f), w1 * fmaxf(eh11.y, 0.f)};
            aeh0 += r00 + r10; aeh1 += r01 + r11;
            v2f w0v = {w0, w0}, w1v = {w1, w1};
            acc0 += w0v * (v2f){hv0.x, hv0.y} + w1v * (v2f){hv1.x, hv1.y} + r00 + r10;
            acc1 += w0v * (v2f){hv0.z, hv0.w} + w1v * (v2f){hv1.z, hv1.w} + r01 + r11;
        }
    }
    *reinterpret_cast<uint2*>(agg   + (size_t)v * H + c) = pack_half4(make_float4(acc0.x, acc0.y, acc1.x, acc1.y));
    *reinterpret_cast<uint2*>(aggeh + (size_t)v * H + c) = pack_half4(make_float4(aeh0.x, aeh0.y, aeh1.x, aeh1.y));
}

// =====================================================================
// CSR message pass: agg = aggeh + sum w*h[src].
// LIST=0: v = block-derived node id (all nodes).
// LIST=1: v = list[i], i bounded by *cnt_p (needed nodes only).
// =====================================================================
template<int LIST>
__global__ __launch_bounds__(256)
void k_msg_csr(const int* __restrict__ off, const int* __restrict__ deg,
               const int2* __restrict__ epk, const __half* __restrict__ aggeh,
               const float* __restrict__ h, __half* __restrict__ agg,
               const int* __restrict__ list, const int* __restrict__ cnt_p,
               int nnodes) {
    const int hw = threadIdx.x >> 5;
    const int ln = threadIdx.x & 31;
    const int c  = ln * 4;
    int i = blockIdx.x * 8 + hw;
    int bound = LIST ? *cnt_p : nnodes;
    if (i >= bound) return;
    int v = LIST ? list[i] : i;
    float4 a0 = unpack_half4(*reinterpret_cast<const uint2*>(aggeh + (size_t)v * H + c));
    v2f acc0 = {a0.x, a0.y}, acc1 = {a0.z, a0.w};
    const int o = off[v], d = deg[v];
    for (int jb = 0; jb < d; jb += 32) {
        const int nn = min(32, d - jb);
        int2 meta = make_int2(0, 0);
        if (ln < nn) meta = epk[o + jb + ln];
        const int ms = meta.x;
        const float mw = __int_as_float(meta.y);
        for (int q = 0; q < nn; q += 4) {
            #pragma unroll
            for (int u = 0; u < 4; ++u) {
                int qq = q + u;
                int   s = __shfl(ms, qq, 32);
                float w = __shfl(mw, qq, 32);
                if (qq >= nn) { s = 0; w = 0.f; }
                float4 hv = *reinterpret_cast<const float4*>(h + (size_t)s * H + c);
                v2f wv = {w, w};
                acc0 += wv * (v2f){hv.x, hv.y};
                acc1 += wv * (v2f){hv.z, hv.w};
            }
        }
    }
    *reinterpret_cast<uint2*>(agg + (size_t)v * H + c) = pack_half4(make_float4(acc0.x, acc0.y, acc1.x, acc1.y));
}

// =====================================================================
// h = relu(h + agg @ w_mp + b_mp), in place; agg fp16; scalar microkernel.
// LIST=1: rows indirected through list, bounded by *cnt_p.
// =====================================================================
template<int LIST>
__global__ __launch_bounds__(256)
void k_gemm_update(const __half* __restrict__ agg, int nrows,
                   const float* __restrict__ w, const float* __restrict__ bias,
                   float* __restrict__ h,
                   const int* __restrict__ list, const int* __restrict__ cnt_p) {
    __shared__ float w_lds[32][H];
    __shared__ float a_lds[32][APAD];
    __shared__ int   m_lds[128];
    const int tid = threadIdx.x;
    const int rbase = blockIdx.x * 128;
    const int bound = LIST ? *cnt_p : nrows;
    if (rbase >= bound) return;
    if (LIST && tid < 128) {
        int r = rbase + tid;
        m_lds[tid] = (r < bound) ? list[r] : 0;
    }
    const int tx = tid & 15, ty = tid >> 4;
    float acc[8][8] = {};
    for (int kc = 0; kc < 4; ++kc) {
        const int k0 = kc * 32;
        __syncthreads();
        for (int i = tid; i < 1024; i += 256) {
            int kk = i >> 5, c4 = i & 31;
            *reinterpret_cast<float4*>(&w_lds[kk][c4 * 4]) =
                reinterpret_cast<const float4*>(w + (size_t)(k0 + kk) * H)[c4];
        }
        for (int i = tid; i < 1024; i += 256) {
            int r = i >> 3, f = i & 7;
            int row = rbase + r;
            float4 v = make_float4(0.f, 0.f, 0.f, 0.f);
            if (row < bound) {
                int hr = LIST ? m_lds[r] : row;
                v = unpack_half4(reinterpret_cast<const uint2*>(agg + (size_t)hr * H + k0)[f]);
            }
            a_lds[f * 4 + 0][r] = v.x;
            a_lds[f * 4 + 1][r] = v.y;
            a_lds[f * 4 + 2][r] = v.z;
            a_lds[f * 4 + 3][r] = v.w;
        }
        __syncthreads();
        #pragma unroll 4
        for (int k = 0; k < 32; ++k) {
            float4 a0 = *reinterpret_cast<const float4*>(&a_lds[k][ty * 8]);
            float4 a1 = *reinterpret_cast<const float4*>(&a_lds[k][ty * 8 + 4]);
            float4 w0 = *reinterpret_cast<const float4*>(&w_lds[k][tx * 4]);
            float4 w1 = *reinterpret_cast<const float4*>(&w_lds[k][64 + tx * 4]);
            float aa[8] = {a0.x, a0.y, a0.z, a0.w, a1.x, a1.y, a1.z, a1.w};
            float ww[8] = {w0.x, w0.y, w0.z, w0.w, w1.x, w1.y, w1.z, w1.w};
            #pragma unroll
            for (int i2 = 0; i2 < 8; ++i2)
                #pragma unroll
                for (int j = 0; j < 8; ++j)
                    acc[i2][j] += aa[i2] * ww[j];
        }
    }
    float4 b0 = *reinterpret_cast<const float4*>(bias + tx * 4);
    float4 b1 = *reinterpret_cast<const float4*>(bias + 64 + tx * 4);
    float bb[8] = {b0.x, b0.y, b0.z, b0.w, b1.x, b1.y, b1.z, b1.w};
    #pragma unroll
    for (int i2 = 0; i2 < 8; ++i2) {
        int row = rbase + ty * 8 + i2;
        if (row < bound) {
            int hr = LIST ? m_lds[ty * 8 + i2] : row;
            float* hp = h + (size_t)hr * H + tx * 4;
            float4 h0 = *reinterpret_cast<const float4*>(hp);
            float4 h1 = *reinterpret_cast<const float4*>(hp + 64);
            float4 o0, o1;
            o0.x = fmaxf(h0.x + acc[i2][0] + bb[0], 0.f); o0.y = fmaxf(h0.y + acc[i2][1] + bb[1], 0.f);
            o0.z = fmaxf(h0.z + acc[i2][2] + bb[2], 0.f); o0.w = fmaxf(h0.w + acc[i2][3] + bb[3], 0.f);
            o1.x = fmaxf(h1.x + acc[i2][4] + bb[4], 0.f); o1.y = fmaxf(h1.y + acc[i2][5] + bb[5], 0.f);
            o1.z = fmaxf(h1.z + acc[i2][6] + bb[6], 0.f); o1.w = fmaxf(h1.w + acc[i2][7] + bb[7], 0.f);
            *reinterpret_cast<float4*>(hp)      = o0;
            *reinterpret_cast<float4*>(hp + 64) = o1;
        }
    }
}

// =====================================================================
// Group-CSR pool
// =====================================================================
__global__ __launch_bounds__(256)
void k_ghist(const int* __restrict__ rowmap, const int* __restrict__ batch,
             int* __restrict__ deg_g, int nrows) {
    int r = blockIdx.x * 256 + threadIdx.x;
    if (r < nrows) atomicAdd(&deg_g[batch[rowmap[r]]], 1);
}

__global__ __launch_bounds__(256)
void k_gscan(const int* __restrict__ deg, int* __restrict__ off, int* __restrict__ cur) {
    __shared__ int tsum[256];
    const int tid = threadIdx.x;
    int local[4]; int s = 0;
    #pragma unroll
    for (int j = 0; j < 4; ++j) { local[j] = deg[tid * 4 + j]; s += local[j]; }
    tsum[tid] = s;
    __syncthreads();
    for (int d = 1; d < 256; d <<= 1) {
        int v = (tid >= d) ? tsum[tid - d] : 0;
        __syncthreads();
        tsum[tid] += v;
        __syncthreads();
    }
    int excl = tsum[tid] - s;
    #pragma unroll
    for (int j = 0; j < 4; ++j) {
        off[tid * 4 + j] = excl;
        cur[tid * 4 + j] = excl;
        excl += local[j];
    }
}

template<bool GATHER>
__global__ __launch_bounds__(256)
void k_gscatter(const int* __restrict__ rowmap, const int* __restrict__ batch,
                const float* __restrict__ nodew, int* __restrict__ cur,
                int* __restrict__ prow, float* __restrict__ pnw, int nrows) {
    int r = blockIdx.x * 256 + threadIdx.x;
    if (r >= nrows) return;
    int oid = rowmap[r];
    int g = batch[oid];
    int pos = atomicAdd(&cur[g], 1);
    prow[pos] = GATHER ? oid : r;
    pnw[pos]  = nodew[oid];
}

__global__ __launch_bounds__(256)
void k_pool(const int* __restrict__ off_g, const int* __restrict__ deg_g,
            const int* __restrict__ prow, const float* __restrict__ pnw,
            const float* __restrict__ h,
            const float* __restrict__ w, const float* __restrict__ bias,
            float* __restrict__ outp) {
    __shared__ float s_lds[4][H];
    __shared__ float ssum[H];
    __shared__ float r_lds[2][H];
    __shared__ float cg_lds[4];
    const int g = blockIdx.x;
    const int o = off_g[g], cnt = deg_g[g];
    const int wv = threadIdx.x >> 6, lane = threadIdx.x & 63;
    float ax = 0.f, ay = 0.f, cg = 0.f;
    for (int i = wv; i < cnt; i += 4) {
        int hrow = prow[o + i];
        float nw = pnw[o + i];
        float2 v = *reinterpret_cast<const float2*>(h + (size_t)hrow * H + lane * 2);
        ax += nw * v.x; ay += nw * v.y; cg += nw;
    }
    s_lds[wv][lane * 2]     = ax;
    s_lds[wv][lane * 2 + 1] = ay;
    if (lane == 0) cg_lds[wv] = cg;
    __syncthreads();
    if (threadIdx.x < H)
        ssum[threadIdx.x] = s_lds[0][threadIdx.x] + s_lds[1][threadIdx.x]
                          + s_lds[2][threadIdx.x] + s_lds[3][threadIdx.x];
    __syncthreads();
    const int c = threadIdx.x & 127, kh = threadIdx.x >> 7;
    float p = 0.f;
    #pragma unroll 8
    for (int k = 0; k < 64; ++k)
        p += ssum[kh * 64 + k] * w[(size_t)(kh * 64 + k) * H + c];
    r_lds[kh][c] = p;
    __syncthreads();
    if (threadIdx.x < H) {
        float cga = cg_lds[0] + cg_lds[1] + cg_lds[2] + cg_lds[3];
        float val = r_lds[0][c] + r_lds[1][c] + bias[c] * cga;
        outp[(size_t)g * H + c] = val / fmaxf((float)cnt, 1.f);
    }
}

extern "C" void kernel_launch(void* const* d_in, const int* in_sizes, int n_in,
                              void* d_out, int out_size, void* d_ws, size_t ws_size,
                              hipStream_t stream) {
    (void)n_in; (void)out_size; (void)ws_size;
    const float* x           = (const float*)d_in[0];
    const float* node_weight = (const float*)d_in[1];
    const int*   edge_index  = (const int*)d_in[2];
    const float* edge_attr   = (const float*)d_in[3];
    const float* edge_weight = (const float*)d_in[4];
    const int*   batch       = (const int*)d_in[5];
    const int*   cnm         = (const int*)d_in[6];
    const int*   tnm         = (const int*)d_in[7];
    const int*   csub        = (const int*)d_in[8];
    const int*   sem         = (const int*)d_in[9];
    const void*  cmask       = d_in[10];

    const float* ctx_w_node = (const float*)d_in[11];
    const float* ctx_b_node = (const float*)d_in[12];
    const float* ctx_w_edge = (const float*)d_in[13];
    const float* ctx_b_edge = (const float*)d_in[14];
    const float* ctx_w_mp   = (const float*)d_in[15];
    const float* ctx_b_mp   = (const float*)d_in[16];
    const float* ctx_w_out  = (const float*)d_in[17];
    const float* ctx_b_out  = (const float*)d_in[18];
    const float* tgt_w_node = (const float*)d_in[19];
    const float* tgt_b_node = (const float*)d_in[20];
    const float* tgt_w_edge = (const float*)d_in[21];
    const float* tgt_b_edge = (const float*)d_in[22];
    const float* tgt_w_mp   = (const float*)d_in[23];
    const float* tgt_b_mp   = (const float*)d_in[24];
    const float* tgt_w_out  = (const float*)d_in[25];
    const float* tgt_b_out  = (const float*)d_in[26];

    const int N  = in_sizes[1];
    const int E  = in_sizes[4];
    const int NC = in_sizes[6];
    const int NT = in_sizes[7];
    const int ES = in_sizes[9];
    const int NMAX = (NT > NC) ? NT : NC;

    float* out = (float*)d_out;

    // ---------------- workspace layout ----------------
    char* ws = (char*)d_ws;
    float*  h     = (float*)ws;  ws += (size_t)N * H * sizeof(float);
    __half* agg   = (__half*)ws; ws += (size_t)N * H * sizeof(__half);
    __half* aggeh = (__half*)ws; ws += (size_t)N * H * sizeof(__half);
    int2*  epk    = (int2*)ws;   ws += (size_t)E * sizeof(int2);
    int2*  epkh   = (int2*)ws;   ws += (size_t)E * sizeof(int2);
    int*   deg    = (int*)ws;    ws += (size_t)N * sizeof(int);
    int*   off    = (int*)ws;    ws += (size_t)N * sizeof(int);
    int*   cur    = (int*)ws;    ws += (size_t)N * sizeof(int);
    int*   nflag  = (int*)ws;    ws += (size_t)N * sizeof(int);   // contiguous with ncnt
    int*   ncnt   = (int*)ws;    ws += sizeof(int);
    int*   nlist  = (int*)ws;    ws += (size_t)N * sizeof(int);
    int*   bsum   = (int*)ws;    ws += 1024 * sizeof(int);
    int*   deg_g  = (int*)ws;    ws += NG * sizeof(int);
    int*   off_g  = (int*)ws;    ws += NG * sizeof(int);
    int*   cur_g  = (int*)ws;    ws += NG * sizeof(int);
    int*   prow   = (int*)ws;    ws += (size_t)NMAX * sizeof(int);
    float* pnw    = (float*)ws;  ws += (size_t)NMAX * sizeof(float);
    int*   flag   = (int*)ws;    ws += sizeof(int);

    int nwords = ES / 4; if (nwords > 8192) nwords = 8192;
    k_sniff<<<1, 256, 0, stream>>>((const unsigned int*)cmask, nwords, flag);

    // ================= FULL graph pass (tgt params) =================
    {
        const int* fsrc = edge_index;
        const int* fdst = edge_index + E;
        hipMemsetAsync(deg, 0, (size_t)N * sizeof(int), stream);
        hipMemsetAsync(nflag, 0, ((size_t)N + 1) * sizeof(int), stream);   // nflag + ncnt
        int egrid = (E + 255) / 256;
        k_hist<0><<<egrid, 256, 0, stream>>>(fdst, edge_weight, nullptr, nullptr, nullptr, deg, E);
        int nb1 = (N + 1023) / 1024;
        k_scan1<<<nb1, 256, 0, stream>>>(deg, off, bsum, N);
        k_scan2<<<1, 256, 0, stream>>>(bsum, nb1);
        k_scan3<<<(N + 255) / 256, 256, 0, stream>>>(bsum, off, cur, N);
        k_scatter<0><<<egrid, 256, 0, stream>>>(fsrc, fdst, edge_weight, nullptr, nullptr, nullptr,
                                                cur, epk, epkh, E);
        // needed-node list for the last MP step
        k_mark<<<(NT + 255) / 256, 256, 0, stream>>>(tnm, nflag, NT);
        k_compact<<<(N + 255) / 256, 256, 0, stream>>>(nflag, nlist, ncnt, N);

        k_gemm_enc<false><<<(N + 127) / 128, 256, 0, stream>>>(x, nullptr, N, tgt_w_node, tgt_b_node, h);
        k_msg_eh<<<(N + 7) / 8, 256, 0, stream>>>(off, deg, epk, epkh, edge_attr,
                                                  tgt_w_edge, tgt_b_edge, h, agg, aggeh, N);
        k_gemm_update<0><<<(N + 127) / 128, 256, 0, stream>>>(agg, N, tgt_w_mp, tgt_b_mp, h,
                                                              nullptr, nullptr);
        // t = 1 (full)
        k_msg_csr<0><<<(N + 7) / 8, 256, 0, stream>>>(off, deg, epk, aggeh, h, agg, nullptr, nullptr, N);
        k_gemm_update<0><<<(N + 127) / 128, 256, 0, stream>>>(agg, N, tgt_w_mp + H * H, tgt_b_mp + H, h,
                                                              nullptr, nullptr);
        // t = 2 (only nodes read by the pool)
        k_msg_csr<1><<<(N + 7) / 8, 256, 0, stream>>>(off, deg, epk, aggeh, h, agg, nlist, ncnt, N);
        k_gemm_update<1><<<(N + 127) / 128, 256, 0, stream>>>(agg, N, tgt_w_mp + 2 * H * H, tgt_b_mp + 2 * H, h,
                                                              nlist, ncnt);
        hipMemsetAsync(deg_g, 0, NG * sizeof(int), stream);
        k_ghist<<<(NT + 255) / 256, 256, 0, stream>>>(tnm, batch, deg_g, NT);
        k_gscan<<<1, 256, 0, stream>>>(deg_g, off_g, cur_g);
        k_gscatter<true><<<(NT + 255) / 256, 256, 0, stream>>>(tnm, batch, node_weight, cur_g, prow, pnw, NT);
        k_pool<<<NG, 256, 0, stream>>>(off_g, deg_g, prow, pnw, h, tgt_w_out, tgt_b_out,
                                       out + (size_t)NG * H);
    }

    // ================= CTX subgraph pass (ctx params) =================
    {
        const int* csrc = csub;
        const int* cdst = csub + ES;
        hipMemsetAsync(deg, 0, (size_t)NC * sizeof(int), stream);
        int egrid = (ES + 255) / 256;
        k_hist<1><<<egrid, 256, 0, stream>>>(cdst, edge_weight, sem, cmask, flag, deg, ES);
        int nb1 = (NC + 1023) / 1024;
        k_scan1<<<nb1, 256, 0, stream>>>(deg, off, bsum, NC);
        k_scan2<<<1, 256, 0, stream>>>(bsum, nb1);
        k_scan3<<<(NC + 255) / 256, 256, 0, stream>>>(bsum, off, cur, NC);
        k_scatter<1><<<egrid, 256, 0, stream>>>(csrc, cdst, edge_weight, sem, cmask, flag,
                                                cur, epk, epkh, ES);
        k_gemm_enc<true><<<(NC + 127) / 128, 256, 0, stream>>>(x, cnm, NC, ctx_w_node, ctx_b_node, h);
        k_msg_eh<<<(NC + 7) / 8, 256, 0, stream>>>(off, deg, epk, epkh, edge_attr,
                                                   ctx_w_edge, ctx_b_edge, h, agg, aggeh, NC);
        k_gemm_update<0><<<(NC + 127) / 128, 256, 0, stream>>>(agg, NC, ctx_w_mp, ctx_b_mp, h,
                                                               nullptr, nullptr);
        for (int t = 1; t < 3; ++t) {
            k_msg_csr<0><<<(NC + 7) / 8, 256, 0, stream>>>(off, deg, epk, aggeh, h, agg, nullptr, nullptr, NC);
            k_gemm_update<0><<<(NC + 127) / 128, 256, 0, stream>>>(agg, NC,
                                                                   ctx_w_mp + t * H * H, ctx_b_mp + t * H, h,
                                                                   nullptr, nullptr);
        }
        hipMemsetAsync(deg_g, 0, NG * sizeof(int), stream);
        k_ghist<<<(NC + 255) / 256, 256, 0, stream>>>(cnm, batch, deg_g, NC);
        k_gscan<<<1, 256, 0, stream>>>(deg_g, off_g, cur_g);
        k_gscatter<false><<<(NC + 255) / 256, 256, 0, stream>>>(cnm, batch, node_weight, cur_g, prow, pnw, NC);
        k_pool<<<NG, 256, 0, stream>>>(off_g, deg_g, prow, pnw, h, ctx_w_out, ctx_b_out, out);
    }
}

// Round 18
// 1495.573 us; speedup vs baseline: 1.0352x; 1.0021x over previous
//
#include <hip/hip_runtime.h>
#include <hip/hip_fp16.h>
#include <stdint.h>

#define H 128
#define FN 133
#define FE 14
#define NG 1024
#define APAD 133

typedef float v2f __attribute__((ext_vector_type(2)));

// ---------------- fp16x4 pack/unpack ----------------
__device__ __forceinline__ uint2 pack_half4(float4 v) {
    __half2 a = __float22half2_rn(make_float2(v.x, v.y));
    __half2 b = __float22half2_rn(make_float2(v.z, v.w));
    uint2 r;
    r.x = *reinterpret_cast<unsigned int*>(&a);
    r.y = *reinterpret_cast<unsigned int*>(&b);
    return r;
}
__device__ __forceinline__ float4 unpack_half4(uint2 u) {
    __half2 a = *reinterpret_cast<__half2*>(&u.x);
    __half2 b = *reinterpret_cast<__half2*>(&u.y);
    float2 fa = __half22float2(a);
    float2 fb = __half22float2(b);
    return make_float4(fa.x, fa.y, fb.x, fb.y);
}

// ---------------- mask dtype sniff ----------------
__global__ void k_sniff(const unsigned int* __restrict__ w, int nwords, int* __restrict__ flag) {
    __shared__ int sawFloat, sawBig;
    if (threadIdx.x == 0) { sawFloat = 0; sawBig = 0; }
    __syncthreads();
    int f = 0, bg = 0;
    for (int i = threadIdx.x; i < nwords; i += blockDim.x) {
        unsigned int v = w[i];
        if (v == 0u || v == 1u) continue;
        if (v == 0x3F800000u) f = 1; else bg = 1;
    }
    if (f) atomicOr(&sawFloat, 1);
    if (bg) atomicOr(&sawBig, 1);
    __syncthreads();
    if (threadIdx.x == 0) *flag = sawBig ? 1 : (sawFloat ? 2 : 0);
}

__device__ __forceinline__ float mask_val(const void* mask, int mm, long e) {
    if (mm == 1)      return ((const unsigned char*)mask)[e] ? 1.f : 0.f;
    else if (mm == 2) return ((const float*)mask)[e];
    else              return ((const int*)mask)[e] ? 1.f : 0.f;
}

// =====================================================================
// Node encoder: h = relu(x[map?] @ w + b), K = 133 (5 zero-padded chunks)
// 64-row tile: LDS 25.1KB -> 6 blocks/CU (75% occ ceiling), acc 4x8,
// same scalar microkernel + col-split w-reads. a_lds pad 69 (coprime 32).
// =====================================================================
template<bool GATHER>
__global__ __launch_bounds__(256)
void k_gemm_enc(const float* __restrict__ x, const int* __restrict__ map, int nrows,
                const float* __restrict__ w, const float* __restrict__ bias,
                float* __restrict__ hout) {
    __shared__ float w_lds[32][H];
    __shared__ float a_lds[32][69];
    __shared__ int   m_lds[64];
    const int tid = threadIdx.x;
    const int rbase = blockIdx.x * 64;
    if (GATHER && tid < 64) {
        int row = rbase + tid;
        m_lds[tid] = (row < nrows) ? map[row] : 0;
    }
    const int tx = tid & 15, ty = tid >> 4;
    float acc[4][8] = {};
    for (int kc = 0; kc < 5; ++kc) {
        const int k0 = kc * 32;
        __syncthreads();
        for (int i = tid; i < 1024; i += 256) {
            int kk = i >> 5, c4 = i & 31;
            float4 v = make_float4(0.f, 0.f, 0.f, 0.f);
            if (k0 + kk < FN)
                v = reinterpret_cast<const float4*>(w + (size_t)(k0 + kk) * H)[c4];
            *reinterpret_cast<float4*>(&w_lds[kk][c4 * 4]) = v;
        }
        for (int i = tid; i < 64 * 32; i += 256) {
            int r = i >> 5, kk = i & 31;
            int row = rbase + r;
            float v = 0.f;
            if (row < nrows && k0 + kk < FN) {
                int sr = GATHER ? m_lds[r] : row;
                v = x[(size_t)sr * FN + k0 + kk];
            }
            a_lds[kk][r] = v;
        }
        __syncthreads();
        #pragma unroll 4
        for (int k = 0; k < 32; ++k) {
            float4 a0 = *reinterpret_cast<const float4*>(&a_lds[k][ty * 4]);
            float4 w0 = *reinterpret_cast<const float4*>(&w_lds[k][tx * 4]);
            float4 w1 = *reinterpret_cast<const float4*>(&w_lds[k][64 + tx * 4]);
            float aa[4] = {a0.x, a0.y, a0.z, a0.w};
            float ww[8] = {w0.x, w0.y, w0.z, w0.w, w1.x, w1.y, w1.z, w1.w};
            #pragma unroll
            for (int i2 = 0; i2 < 4; ++i2)
                #pragma unroll
                for (int j = 0; j < 8; ++j)
                    acc[i2][j] += aa[i2] * ww[j];
        }
    }
    float4 b0 = *reinterpret_cast<const float4*>(bias + tx * 4);
    float4 b1 = *reinterpret_cast<const float4*>(bias + 64 + tx * 4);
    float bb[8] = {b0.x, b0.y, b0.z, b0.w, b1.x, b1.y, b1.z, b1.w};
    #pragma unroll
    for (int i2 = 0; i2 < 4; ++i2) {
        int row = rbase + ty * 4 + i2;
        if (row < nrows) {
            float4 o0, o1;
            o0.x = fmaxf(acc[i2][0] + bb[0], 0.f); o0.y = fmaxf(acc[i2][1] + bb[1], 0.f);
            o0.z = fmaxf(acc[i2][2] + bb[2], 0.f); o0.w = fmaxf(acc[i2][3] + bb[3], 0.f);
            o1.x = fmaxf(acc[i2][4] + bb[4], 0.f); o1.y = fmaxf(acc[i2][5] + bb[5], 0.f);
            o1.z = fmaxf(acc[i2][6] + bb[6], 0.f); o1.w = fmaxf(acc[i2][7] + bb[7], 0.f);
            float* hp = hout + (size_t)row * H + tx * 4;
            *reinterpret_cast<float4*>(hp)      = o0;
            *reinterpret_cast<float4*>(hp + 64) = o1;
        }
    }
}

// =====================================================================
// Edge CSR build
// =====================================================================
template<int MODE>
__global__ __launch_bounds__(256)
void k_hist(const int* __restrict__ dst, const float* __restrict__ edge_weight,
            const int* __restrict__ emap, const void* __restrict__ mask,
            const int* __restrict__ mmode_p, int* __restrict__ deg, int nedges) {
    int e = blockIdx.x * 256 + threadIdx.x;
    if (e >= nedges) return;
    int eo = MODE ? emap[e] : e;
    float w = edge_weight[eo];
    if (MODE) w *= mask_val(mask, *mmode_p, e);
    if (w != 0.f) atomicAdd(&deg[dst[e]], 1);
}

__global__ __launch_bounds__(256)
void k_scan1(const int* __restrict__ deg, int* __restrict__ off, int* __restrict__ bsum, int n) {
    __shared__ int tsum[256];
    const int tid = threadIdx.x;
    const int base = blockIdx.x * 1024;
    int local[4]; int s = 0;
    #pragma unroll
    for (int j = 0; j < 4; ++j) {
        int i = base + tid * 4 + j;
        local[j] = (i < n) ? deg[i] : 0;
        s += local[j];
    }
    tsum[tid] = s;
    __syncthreads();
    for (int d = 1; d < 256; d <<= 1) {
        int v = (tid >= d) ? tsum[tid - d] : 0;
        __syncthreads();
        tsum[tid] += v;
        __syncthreads();
    }
    int excl = tsum[tid] - s;
    #pragma unroll
    for (int j = 0; j < 4; ++j) {
        int i = base + tid * 4 + j;
        if (i < n) off[i] = excl;
        excl += local[j];
    }
    if (tid == 255) bsum[blockIdx.x] = tsum[255];
}

__global__ __launch_bounds__(256)
void k_scan2(int* __restrict__ bsum, int nb) {
    __shared__ int tsum[256];
    const int tid = threadIdx.x;
    int local[4]; int s = 0;
    #pragma unroll
    for (int j = 0; j < 4; ++j) {
        int i = tid * 4 + j;
        local[j] = (i < nb) ? bsum[i] : 0;
        s += local[j];
    }
    tsum[tid] = s;
    __syncthreads();
    for (int d = 1; d < 256; d <<= 1) {
        int v = (tid >= d) ? tsum[tid - d] : 0;
        __syncthreads();
        tsum[tid] += v;
        __syncthreads();
    }
    int excl = tsum[tid] - s;
    #pragma unroll
    for (int j = 0; j < 4; ++j) {
        int i = tid * 4 + j;
        if (i < nb) bsum[i] = excl;
        excl += local[j];
    }
}

__global__ __launch_bounds__(256)
void k_scan3(const int* __restrict__ bsum, int* __restrict__ off, int* __restrict__ cur, int n) {
    int i = blockIdx.x * 256 + threadIdx.x;
    if (i < n) {
        int o = off[i] + bsum[i >> 10];
        off[i] = o;
        cur[i] = o;
    }
}

template<int MODE>
__global__ __launch_bounds__(256)
void k_scatter(const int* __restrict__ src, const int* __restrict__ dst,
               const float* __restrict__ edge_weight,
               const int* __restrict__ emap, const void* __restrict__ mask,
               const int* __restrict__ mmode_p, int* __restrict__ cur,
               int2* __restrict__ epk, int2* __restrict__ epkh,
               int nedges) {
    int e = blockIdx.x * 256 + threadIdx.x;
    if (e >= nedges) return;
    int eo = MODE ? emap[e] : e;
    float w = edge_weight[eo];
    if (MODE) w *= mask_val(mask, *mmode_p, e);
    if (w != 0.f) {
        int pos = atomicAdd(&cur[dst[e]], 1);
        int wb = __float_as_int(w);
        epk[pos]  = make_int2(src[e], wb);
        epkh[pos] = make_int2(eo, wb);
    }
}

// =====================================================================
// Needed-node mark + compact (t=2 set), then 1-hop expansion (t=1 set)
// =====================================================================
__global__ __launch_bounds__(256)
void k_mark(const int* __restrict__ rowmap, int* __restrict__ nflag, int nrows) {
    int r = blockIdx.x * 256 + threadIdx.x;
    if (r < nrows) nflag[rowmap[r]] = 1;
}

__global__ __launch_bounds__(256)
void k_compact(const int* __restrict__ nflag, int* __restrict__ list,
               int* __restrict__ cnt, int n) {
    int i = blockIdx.x * 256 + threadIdx.x;
    bool p = (i < n) && (nflag[i] != 0);
    unsigned long long m = __ballot(p);
    int lane = threadIdx.x & 63;
    int wcount = __popcll(m);
    int base = 0;
    if (lane == 0 && wcount) base = atomicAdd(cnt, wcount);
    base = __shfl(base, 0, 64);
    if (p) {
        int pos = base + (int)__popcll(m & ((1ull << lane) - 1ull));
        list[pos] = i;
    }
}

// mark v and all CSR sources of v, for v in list[0..*cnt_p)
__global__ __launch_bounds__(256)
void k_mark_src(const int* __restrict__ off, const int* __restrict__ deg,
                const int2* __restrict__ epk,
                const int* __restrict__ list, const int* __restrict__ cnt_p,
                int* __restrict__ nflag2) {
    int i = blockIdx.x * 256 + threadIdx.x;
    if (i >= *cnt_p) return;
    int v = list[i];
    nflag2[v] = 1;
    const int o = off[v], d = deg[v];
    for (int j = o; j < o + d; ++j) nflag2[epk[j].x] = 1;
}

// =====================================================================
// Fused t=0 walk (packed fp32 eh math; fp16 outputs)
// =====================================================================
__global__ __launch_bounds__(256)
void k_msg_eh(const int* __restrict__ off, const int* __restrict__ deg,
              const int2* __restrict__ epk, const int2* __restrict__ epkh,
              const float* __restrict__ edge_attr,
              const float* __restrict__ w_edge, const float* __restrict__ b_edge,
              const float* __restrict__ h,
              __half* __restrict__ agg, __half* __restrict__ aggeh, int nnodes) {
    __shared__ float we_lds[FE * H];
    __shared__ float be_lds[H];
    for (int i = threadIdx.x; i < FE * H; i += 256) we_lds[i] = w_edge[i];
    if (threadIdx.x < H) be_lds[threadIdx.x] = b_edge[threadIdx.x];
    __syncthreads();
    const int hw = threadIdx.x >> 5;
    const int ln = threadIdx.x & 31;
    const int c  = ln * 4;
    int v = blockIdx.x * 8 + hw;
    if (v >= nnodes) return;
    v2f acc0 = {0.f, 0.f}, acc1 = {0.f, 0.f};
    v2f aeh0 = {0.f, 0.f}, aeh1 = {0.f, 0.f};
    const int o = off[v], d = deg[v];
    const float4 bev = *reinterpret_cast<const float4*>(be_lds + c);
    const v2f bev0 = {bev.x, bev.y}, bev1 = {bev.z, bev.w};
    for (int jb = 0; jb < d; jb += 32) {
        const int nn = min(32, d - jb);
        int2 m1 = make_int2(0, 0), m2 = make_int2(0, 0);
        if (ln < nn) { m1 = epk[o + jb + ln]; m2 = epkh[o + jb + ln]; }
        const int msrc = m1.x;
        const int meo  = m2.x;
        const float mw = __int_as_float(m1.y);
        for (int q = 0; q < nn; q += 2) {
            int   s0 = __shfl(msrc, q, 32);
            int   e0 = __shfl(meo,  q, 32);
            float w0 = __shfl(mw,   q, 32);
            int   s1 = __shfl(msrc, q + 1, 32);
            int   e1 = __shfl(meo,  q + 1, 32);
            float w1 = __shfl(mw,   q + 1, 32);
            if (q + 1 >= nn) { s1 = s0; e1 = e0; w1 = 0.f; }
            float4 hv0 = *reinterpret_cast<const float4*>(h + (size_t)s0 * H + c);
            float4 hv1 = *reinterpret_cast<const float4*>(h + (size_t)s1 * H + c);
            float a0 = (ln < FE) ? edge_attr[(size_t)e0 * FE + ln] : 0.f;
            float a1 = (ln < FE) ? edge_attr[(size_t)e1 * FE + ln] : 0.f;
            v2f eh00 = bev0, eh01 = bev1, eh10 = bev0, eh11 = bev1;
            #pragma unroll
            for (int k = 0; k < FE; ++k) {
                float f0 = __shfl(a0, k, 32);
                float f1 = __shfl(a1, k, 32);
                float4 wv = *reinterpret_cast<const float4*>(we_lds + k * H + c);
                v2f wva = {wv.x, wv.y}, wvb = {wv.z, wv.w};
                v2f f0v = {f0, f0}, f1v = {f1, f1};
                eh00 += f0v * wva; eh01 += f0v * wvb;
                eh10 += f1v * wva; eh11 += f1v * wvb;
            }
            v2f r00 = {w0 * fmaxf(eh00.x, 0.f), w0 * fmaxf(eh00.y, 0.f)};
            v2f r01 = {w0 * fmaxf(eh01.x, 0.f), w0 * fmaxf(eh01.y, 0.f)};
            v2f r10 = {w1 * fmaxf(eh10.x, 0.f), w1 * fmaxf(eh10.y, 0.f)};
            v2f r11 = {w1 * fmaxf(eh11.x, 0.f), w1 * fmaxf(eh11.y, 0.f)};
            aeh0 += r00 + r10; aeh1 += r01 + r11;
            v2f w0v = {w0, w0}, w1v = {w1, w1};
            acc0 += w0v * (v2f){hv0.x, hv0.y} + w1v * (v2f){hv1.x, hv1.y} + r00 + r10;
            acc1 += w0v * (v2f){hv0.z, hv0.w} + w1v * (v2f){hv1.z, hv1.w} + r01 + r11;
        }
    }
    *reinterpret_cast<uint2*>(agg   + (size_t)v * H + c) = pack_half4(make_float4(acc0.x, acc0.y, acc1.x, acc1.y));
    *reinterpret_cast<uint2*>(aggeh + (size_t)v * H + c) = pack_half4(make_float4(aeh0.x, aeh0.y, aeh1.x, aeh1.y));
}

// =====================================================================
// CSR message pass: agg = aggeh + sum w*h[src].
// LIST=1: v = list[i], i bounded by *cnt_p.
// =====================================================================
template<int LIST>
__global__ __launch_bounds__(256)
void k_msg_csr(const int* __restrict__ off, const int* __restrict__ deg,
               const int2* __restrict__ epk, const __half* __restrict__ aggeh,
               const float* __restrict__ h, __half* __restrict__ agg,
               const int* __restrict__ list, const int* __restrict__ cnt_p,
               int nnodes) {
    const int hw = threadIdx.x >> 5;
    const int ln = threadIdx.x & 31;
    const int c  = ln * 4;
    int i = blockIdx.x * 8 + hw;
    int bound = LIST ? *cnt_p : nnodes;
    if (i >= bound) return;
    int v = LIST ? list[i] : i;
    float4 a0 = unpack_half4(*reinterpret_cast<const uint2*>(aggeh + (size_t)v * H + c));
    v2f acc0 = {a0.x, a0.y}, acc1 = {a0.z, a0.w};
    const int o = off[v], d = deg[v];
    for (int jb = 0; jb < d; jb += 32) {
        const int nn = min(32, d - jb);
        int2 meta = make_int2(0, 0);
        if (ln < nn) meta = epk[o + jb + ln];
        const int ms = meta.x;
        const float mw = __int_as_float(meta.y);
        for (int q = 0; q < nn; q += 4) {
            #pragma unroll
            for (int u = 0; u < 4; ++u) {
                int qq = q + u;
                int   s = __shfl(ms, qq, 32);
                float w = __shfl(mw, qq, 32);
                if (qq >= nn) { s = 0; w = 0.f; }
                float4 hv = *reinterpret_cast<const float4*>(h + (size_t)s * H + c);
                v2f wv = {w, w};
                acc0 += wv * (v2f){hv.x, hv.y};
                acc1 += wv * (v2f){hv.z, hv.w};
            }
        }
    }
    *reinterpret_cast<uint2*>(agg + (size_t)v * H + c) = pack_half4(make_float4(acc0.x, acc0.y, acc1.x, acc1.y));
}

// =====================================================================
// h = relu(h + agg @ w_mp + b_mp), in place; agg fp16; scalar microkernel.
// LIST=1: rows indirected through list, bounded by *cnt_p.
// =====================================================================
template<int LIST>
__global__ __launch_bounds__(256)
void k_gemm_update(const __half* __restrict__ agg, int nrows,
                   const float* __restrict__ w, const float* __restrict__ bias,
                   float* __restrict__ h,
                   const int* __restrict__ list, const int* __restrict__ cnt_p) {
    __shared__ float w_lds[32][H];
    __shared__ float a_lds[32][APAD];
    __shared__ int   m_lds[128];
    const int tid = threadIdx.x;
    const int rbase = blockIdx.x * 128;
    const int bound = LIST ? *cnt_p : nrows;
    if (rbase >= bound) return;
    if (LIST && tid < 128) {
        int r = rbase + tid;
        m_lds[tid] = (r < bound) ? list[r] : 0;
    }
    const int tx = tid & 15, ty = tid >> 4;
    float acc[8][8] = {};
    for (int kc = 0; kc < 4; ++kc) {
        const int k0 = kc * 32;
        __syncthreads();
        for (int i = tid; i < 1024; i += 256) {
            int kk = i >> 5, c4 = i & 31;
            *reinterpret_cast<float4*>(&w_lds[kk][c4 * 4]) =
                reinterpret_cast<const float4*>(w + (size_t)(k0 + kk) * H)[c4];
        }
        for (int i = tid; i < 1024; i += 256) {
            int r = i >> 3, f = i & 7;
            int row = rbase + r;
            float4 v = make_float4(0.f, 0.f, 0.f, 0.f);
            if (row < bound) {
                int hr = LIST ? m_lds[r] : row;
                v = unpack_half4(reinterpret_cast<const uint2*>(agg + (size_t)hr * H + k0)[f]);
            }
            a_lds[f * 4 + 0][r] = v.x;
            a_lds[f * 4 + 1][r] = v.y;
            a_lds[f * 4 + 2][r] = v.z;
            a_lds[f * 4 + 3][r] = v.w;
        }
        __syncthreads();
        #pragma unroll 4
        for (int k = 0; k < 32; ++k) {
            float4 a0 = *reinterpret_cast<const float4*>(&a_lds[k][ty * 8]);
            float4 a1 = *reinterpret_cast<const float4*>(&a_lds[k][ty * 8 + 4]);
            float4 w0 = *reinterpret_cast<const float4*>(&w_lds[k][tx * 4]);
            float4 w1 = *reinterpret_cast<const float4*>(&w_lds[k][64 + tx * 4]);
            float aa[8] = {a0.x, a0.y, a0.z, a0.w, a1.x, a1.y, a1.z, a1.w};
            float ww[8] = {w0.x, w0.y, w0.z, w0.w, w1.x, w1.y, w1.z, w1.w};
            #pragma unroll
            for (int i2 = 0; i2 < 8; ++i2)
                #pragma unroll
                for (int j = 0; j < 8; ++j)
                    acc[i2][j] += aa[i2] * ww[j];
        }
    }
    float4 b0 = *reinterpret_cast<const float4*>(bias + tx * 4);
    float4 b1 = *reinterpret_cast<const float4*>(bias + 64 + tx * 4);
    float bb[8] = {b0.x, b0.y, b0.z, b0.w, b1.x, b1.y, b1.z, b1.w};
    #pragma unroll
    for (int i2 = 0; i2 < 8; ++i2) {
        int row = rbase + ty * 8 + i2;
        if (row < bound) {
            int hr = LIST ? m_lds[ty * 8 + i2] : row;
            float* hp = h + (size_t)hr * H + tx * 4;
            float4 h0 = *reinterpret_cast<const float4*>(hp);
            float4 h1 = *reinterpret_cast<const float4*>(hp + 64);
            float4 o0, o1;
            o0.x = fmaxf(h0.x + acc[i2][0] + bb[0], 0.f); o0.y = fmaxf(h0.y + acc[i2][1] + bb[1], 0.f);
            o0.z = fmaxf(h0.z + acc[i2][2] + bb[2], 0.f); o0.w = fmaxf(h0.w + acc[i2][3] + bb[3], 0.f);
            o1.x = fmaxf(h1.x + acc[i2][4] + bb[4], 0.f); o1.y = fmaxf(h1.y + acc[i2][5] + bb[5], 0.f);
            o1.z = fmaxf(h1.z + acc[i2][6] + bb[6], 0.f); o1.w = fmaxf(h1.w + acc[i2][7] + bb[7], 0.f);
            *reinterpret_cast<float4*>(hp)      = o0;
            *reinterpret_cast<float4*>(hp + 64) = o1;
        }
    }
}

// =====================================================================
// Group-CSR pool
// =====================================================================
__global__ __launch_bounds__(256)
void k_ghist(const int* __restrict__ rowmap, const int* __restrict__ batch,
             int* __restrict__ deg_g, int nrows) {
    int r = blockIdx.x * 256 + threadIdx.x;
    if (r < nrows) atomicAdd(&deg_g[batch[rowmap[r]]], 1);
}

__global__ __launch_bounds__(256)
void k_gscan(const int* __restrict__ deg, int* __restrict__ off, int* __restrict__ cur) {
    __shared__ int tsum[256];
    const int tid = threadIdx.x;
    int local[4]; int s = 0;
    #pragma unroll
    for (int j = 0; j < 4; ++j) { local[j] = deg[tid * 4 + j]; s += local[j]; }
    tsum[tid] = s;
    __syncthreads();
    for (int d = 1; d < 256; d <<= 1) {
        int v = (tid >= d) ? tsum[tid - d] : 0;
        __syncthreads();
        tsum[tid] += v;
        __syncthreads();
    }
    int excl = tsum[tid] - s;
    #pragma unroll
    for (int j = 0; j < 4; ++j) {
        off[tid * 4 + j] = excl;
        cur[tid * 4 + j] = excl;
        excl += local[j];
    }
}

template<bool GATHER>
__global__ __launch_bounds__(256)
void k_gscatter(const int* __restrict__ rowmap, const int* __restrict__ batch,
                const float* __restrict__ nodew, int* __restrict__ cur,
                int* __restrict__ prow, float* __restrict__ pnw, int nrows) {
    int r = blockIdx.x * 256 + threadIdx.x;
    if (r >= nrows) return;
    int oid = rowmap[r];
    int g = batch[oid];
    int pos = atomicAdd(&cur[g], 1);
    prow[pos] = GATHER ? oid : r;
    pnw[pos]  = nodew[oid];
}

__global__ __launch_bounds__(256)
void k_pool(const int* __restrict__ off_g, const int* __restrict__ deg_g,
            const int* __restrict__ prow, const float* __restrict__ pnw,
            const float* __restrict__ h,
            const float* __restrict__ w, const float* __restrict__ bias,
            float* __restrict__ outp) {
    __shared__ float s_lds[4][H];
    __shared__ float ssum[H];
    __shared__ float r_lds[2][H];
    __shared__ float cg_lds[4];
    const int g = blockIdx.x;
    const int o = off_g[g], cnt = deg_g[g];
    const int wv = threadIdx.x >> 6, lane = threadIdx.x & 63;
    float ax = 0.f, ay = 0.f, cg = 0.f;
    for (int i = wv; i < cnt; i += 4) {
        int hrow = prow[o + i];
        float nw = pnw[o + i];
        float2 v = *reinterpret_cast<const float2*>(h + (size_t)hrow * H + lane * 2);
        ax += nw * v.x; ay += nw * v.y; cg += nw;
    }
    s_lds[wv][lane * 2]     = ax;
    s_lds[wv][lane * 2 + 1] = ay;
    if (lane == 0) cg_lds[wv] = cg;
    __syncthreads();
    if (threadIdx.x < H)
        ssum[threadIdx.x] = s_lds[0][threadIdx.x] + s_lds[1][threadIdx.x]
                          + s_lds[2][threadIdx.x] + s_lds[3][threadIdx.x];
    __syncthreads();
    const int c = threadIdx.x & 127, kh = threadIdx.x >> 7;
    float p = 0.f;
    #pragma unroll 8
    for (int k = 0; k < 64; ++k)
        p += ssum[kh * 64 + k] * w[(size_t)(kh * 64 + k) * H + c];
    r_lds[kh][c] = p;
    __syncthreads();
    if (threadIdx.x < H) {
        float cga = cg_lds[0] + cg_lds[1] + cg_lds[2] + cg_lds[3];
        float val = r_lds[0][c] + r_lds[1][c] + bias[c] * cga;
        outp[(size_t)g * H + c] = val / fmaxf((float)cnt, 1.f);
    }
}

extern "C" void kernel_launch(void* const* d_in, const int* in_sizes, int n_in,
                              void* d_out, int out_size, void* d_ws, size_t ws_size,
                              hipStream_t stream) {
    (void)n_in; (void)out_size; (void)ws_size;
    const float* x           = (const float*)d_in[0];
    const float* node_weight = (const float*)d_in[1];
    const int*   edge_index  = (const int*)d_in[2];
    const float* edge_attr   = (const float*)d_in[3];
    const float* edge_weight = (const float*)d_in[4];
    const int*   batch       = (const int*)d_in[5];
    const int*   cnm         = (const int*)d_in[6];
    const int*   tnm         = (const int*)d_in[7];
    const int*   csub        = (const int*)d_in[8];
    const int*   sem         = (const int*)d_in[9];
    const void*  cmask       = d_in[10];

    const float* ctx_w_node = (const float*)d_in[11];
    const float* ctx_b_node = (const float*)d_in[12];
    const float* ctx_w_edge = (const float*)d_in[13];
    const float* ctx_b_edge = (const float*)d_in[14];
    const float* ctx_w_mp   = (const float*)d_in[15];
    const float* ctx_b_mp   = (const float*)d_in[16];
    const float* ctx_w_out  = (const float*)d_in[17];
    const float* ctx_b_out  = (const float*)d_in[18];
    const float* tgt_w_node = (const float*)d_in[19];
    const float* tgt_b_node = (const float*)d_in[20];
    const float* tgt_w_edge = (const float*)d_in[21];
    const float* tgt_b_edge = (const float*)d_in[22];
    const float* tgt_w_mp   = (const float*)d_in[23];
    const float* tgt_b_mp   = (const float*)d_in[24];
    const float* tgt_w_out  = (const float*)d_in[25];
    const float* tgt_b_out  = (const float*)d_in[26];

    const int N  = in_sizes[1];
    const int E  = in_sizes[4];
    const int NC = in_sizes[6];
    const int NT = in_sizes[7];
    const int ES = in_sizes[9];
    const int NMAX = (NT > NC) ? NT : NC;

    float* out = (float*)d_out;

    // ---------------- workspace layout ----------------
    char* ws = (char*)d_ws;
    float*  h     = (float*)ws;  ws += (size_t)N * H * sizeof(float);
    __half* agg   = (__half*)ws; ws += (size_t)N * H * sizeof(__half);
    __half* aggeh = (__half*)ws; ws += (size_t)N * H * sizeof(__half);
    int2*  epk    = (int2*)ws;   ws += (size_t)E * sizeof(int2);
    int2*  epkh   = (int2*)ws;   ws += (size_t)E * sizeof(int2);
    int*   deg    = (int*)ws;    ws += (size_t)N * sizeof(int);
    int*   off    = (int*)ws;    ws += (size_t)N * sizeof(int);
    int*   cur    = (int*)ws;    ws += (size_t)N * sizeof(int);
    // nflag, ncnt, nflag2, ncnt2 contiguous -> single memset
    int*   nflag  = (int*)ws;    ws += (size_t)N * sizeof(int);
    int*   ncnt   = (int*)ws;    ws += sizeof(int);
    int*   nflag2 = (int*)ws;    ws += (size_t)N * sizeof(int);
    int*   ncnt2  = (int*)ws;    ws += sizeof(int);
    int*   nlist  = (int*)ws;    ws += (size_t)N * sizeof(int);
    int*   nlist2 = (int*)ws;    ws += (size_t)N * sizeof(int);
    int*   bsum   = (int*)ws;    ws += 1024 * sizeof(int);
    int*   deg_g  = (int*)ws;    ws += NG * sizeof(int);
    int*   off_g  = (int*)ws;    ws += NG * sizeof(int);
    int*   cur_g  = (int*)ws;    ws += NG * sizeof(int);
    int*   prow   = (int*)ws;    ws += (size_t)NMAX * sizeof(int);
    float* pnw    = (float*)ws;  ws += (size_t)NMAX * sizeof(float);
    int*   flag   = (int*)ws;    ws += sizeof(int);

    int nwords = ES / 4; if (nwords > 8192) nwords = 8192;
    k_sniff<<<1, 256, 0, stream>>>((const unsigned int*)cmask, nwords, flag);

    // ================= FULL graph pass (tgt params) =================
    {
        const int* fsrc = edge_index;
        const int* fdst = edge_index + E;
        hipMemsetAsync(deg, 0, (size_t)N * sizeof(int), stream);
        hipMemsetAsync(nflag, 0, (2 * (size_t)N + 2) * sizeof(int), stream);
        int egrid = (E + 255) / 256;
        k_hist<0><<<egrid, 256, 0, stream>>>(fdst, edge_weight, nullptr, nullptr, nullptr, deg, E);
        int nb1 = (N + 1023) / 1024;
        k_scan1<<<nb1, 256, 0, stream>>>(deg, off, bsum, N);
        k_scan2<<<1, 256, 0, stream>>>(bsum, nb1);
        k_scan3<<<(N + 255) / 256, 256, 0, stream>>>(bsum, off, cur, N);
        k_scatter<0><<<egrid, 256, 0, stream>>>(fsrc, fdst, edge_weight, nullptr, nullptr, nullptr,
                                                cur, epk, epkh, E);
        // t=2 set, then 1-hop expanded t=1 set
        k_mark<<<(NT + 255) / 256, 256, 0, stream>>>(tnm, nflag, NT);
        k_compact<<<(N + 255) / 256, 256, 0, stream>>>(nflag, nlist, ncnt, N);
        k_mark_src<<<(N + 255) / 256, 256, 0, stream>>>(off, deg, epk, nlist, ncnt, nflag2);
        k_compact<<<(N + 255) / 256, 256, 0, stream>>>(nflag2, nlist2, ncnt2, N);

        k_gemm_enc<false><<<(N + 63) / 64, 256, 0, stream>>>(x, nullptr, N, tgt_w_node, tgt_b_node, h);
        k_msg_eh<<<(N + 7) / 8, 256, 0, stream>>>(off, deg, epk, epkh, edge_attr,
                                                  tgt_w_edge, tgt_b_edge, h, agg, aggeh, N);
        k_gemm_update<0><<<(N + 127) / 128, 256, 0, stream>>>(agg, N, tgt_w_mp, tgt_b_mp, h,
                                                              nullptr, nullptr);
        // t = 1 (1-hop neighborhood of pooled nodes)
        k_msg_csr<1><<<(N + 7) / 8, 256, 0, stream>>>(off, deg, epk, aggeh, h, agg, nlist2, ncnt2, N);
        k_gemm_update<1><<<(N + 127) / 128, 256, 0, stream>>>(agg, N, tgt_w_mp + H * H, tgt_b_mp + H, h,
                                                              nlist2, ncnt2);
        // t = 2 (pooled nodes only)
        k_msg_csr<1><<<(N + 7) / 8, 256, 0, stream>>>(off, deg, epk, aggeh, h, agg, nlist, ncnt, N);
        k_gemm_update<1><<<(N + 127) / 128, 256, 0, stream>>>(agg, N, tgt_w_mp + 2 * H * H, tgt_b_mp + 2 * H, h,
                                                              nlist, ncnt);
        hipMemsetAsync(deg_g, 0, NG * sizeof(int), stream);
        k_ghist<<<(NT + 255) / 256, 256, 0, stream>>>(tnm, batch, deg_g, NT);
        k_gscan<<<1, 256, 0, stream>>>(deg_g, off_g, cur_g);
        k_gscatter<true><<<(NT + 255) / 256, 256, 0, stream>>>(tnm, batch, node_weight, cur_g, prow, pnw, NT);
        k_pool<<<NG, 256, 0, stream>>>(off_g, deg_g, prow, pnw, h, tgt_w_out, tgt_b_out,
                                       out + (size_t)NG * H);
    }

    // ================= CTX subgraph pass (ctx params) =================
    {
        const int* csrc = csub;
        const int* cdst = csub + ES;
        hipMemsetAsync(deg, 0, (size_t)NC * sizeof(int), stream);
        int egrid = (ES + 255) / 256;
        k_hist<1><<<egrid, 256, 0, stream>>>(cdst, edge_weight, sem, cmask, flag, deg, ES);
        int nb1 = (NC + 1023) / 1024;
        k_scan1<<<nb1, 256, 0, stream>>>(deg, off, bsum, NC);
        k_scan2<<<1, 256, 0, stream>>>(bsum, nb1);
        k_scan3<<<(NC + 255) / 256, 256, 0, stream>>>(bsum, off, cur, NC);
        k_scatter<1><<<egrid, 256, 0, stream>>>(csrc, cdst, edge_weight, sem, cmask, flag,
                                                cur, epk, epkh, ES);
        k_gemm_enc<true><<<(NC + 63) / 64, 256, 0, stream>>>(x, cnm, NC, ctx_w_node, ctx_b_node, h);
        k_msg_eh<<<(NC + 7) / 8, 256, 0, stream>>>(off, deg, epk, epkh, edge_attr,
                                                   ctx_w_edge, ctx_b_edge, h, agg, aggeh, NC);
        k_gemm_update<0><<<(NC + 127) / 128, 256, 0, stream>>>(agg, NC, ctx_w_mp, ctx_b_mp, h,
                                                               nullptr, nullptr);
        for (int t = 1; t < 3; ++t) {
            k_msg_csr<0><<<(NC + 7) / 8, 256, 0, stream>>>(off, deg, epk, aggeh, h, agg, nullptr, nullptr, NC);
            k_gemm_update<0><<<(NC + 127) / 128, 256, 0, stream>>>(agg, NC,
                                                                   ctx_w_mp + t * H * H, ctx_b_mp + t * H, h,
                                                                   nullptr, nullptr);
        }
        hipMemsetAsync(deg_g, 0, NG * sizeof(int), stream);
        k_ghist<<<(NC + 255) / 256, 256, 0, stream>>>(cnm, batch, deg_g, NC);
        k_gscan<<<1, 256, 0, stream>>>(deg_g, off_g, cur_g);
        k_gscatter<false><<<(NC + 255) / 256, 256, 0, stream>>>(cnm, batch, node_weight, cur_g, prow, pnw, NC);
        k_pool<<<NG, 256, 0, stream>>>(off_g, deg_g, prow, pnw, h, ctx_w_out, ctx_b_out, out);
    }
}